// Round 4
// baseline (2015.762 us; speedup 1.0000x reference)
//
#include <hip/hip_runtime.h>
#include <math.h>

typedef __bf16 bf16;
typedef __bf16 bf16x4 __attribute__((ext_vector_type(4)));
typedef __bf16 bf16x8 __attribute__((ext_vector_type(8)));
typedef float f32x4 __attribute__((ext_vector_type(4)));

#define M0   120000
#define M0P  120064   // 938*128
#define K0   768
#define HID  512
#define NREL 5
#define N1   30000
#define N1P  30080    // 235*128
#define E0   600000
#define N2   8000
#define N2P  8064     // 63*128
#define E1   150000
#define OUTC 153
#define OUTP 256

#define GLOAD_LDS16(g, s) \
  __builtin_amdgcn_global_load_lds((const __attribute__((address_space(1))) void*)(g), \
                                   (__attribute__((address_space(3))) void*)(s), 16, 0, 0)

// ---------------------------------------------------------------------------
// GEMM: C[M x N] = A[M x K](bf16 rm) * Bt[N x K](bf16 rm)^T
// MODE 1: store f32, ldc=N. MODE 2: f32+bias, guarded, ldc param.
// ---------------------------------------------------------------------------
template <int MODE>
__global__ __launch_bounds__(256) void gemm_bt(
    const bf16* __restrict__ A, const bf16* __restrict__ Bt, void* __restrict__ Cout,
    int N, int K, int Mv, int Nv, int ldc, const float* __restrict__ bias)
{
  __shared__ __attribute__((aligned(16))) bf16 As[128 * 32];
  __shared__ __attribute__((aligned(16))) bf16 Bs[128 * 32];
  const int tid = threadIdx.x;
  const int w = tid >> 6, l = tid & 63;
  const int tm = blockIdx.x * 128, tn = blockIdx.y * 128;
  const int wm = (w >> 1) * 64, wn = (w & 1) * 64;
  const int lr = l & 15, q = l >> 4;

  f32x4 acc[4][4] = {};

  const int arow = l >> 2;
  const int acol = (l & 3) * 8;
  const bf16* Ag = A + (size_t)tm * K + acol;
  const bf16* Bg = Bt + (size_t)tn * K + acol;

  for (int k0 = 0; k0 < K; k0 += 32) {
#pragma unroll
    for (int i = 0; i < 2; i++) {
      int rb = __builtin_amdgcn_readfirstlane(16 * (2 * w + i));
      GLOAD_LDS16(Ag + (size_t)(rb + arow) * K + k0, As + rb * 32);
      GLOAD_LDS16(Bg + (size_t)(rb + arow) * K + k0, Bs + rb * 32);
    }
    __syncthreads();
    bf16x8 af[4], bfr[4];
#pragma unroll
    for (int i = 0; i < 4; i++)
      af[i] = *(const bf16x8*)&As[(wm + i * 16 + lr) * 32 + q * 8];
#pragma unroll
    for (int jj = 0; jj < 4; jj++)
      bfr[jj] = *(const bf16x8*)&Bs[(wn + jj * 16 + lr) * 32 + q * 8];
#pragma unroll
    for (int i = 0; i < 4; i++)
#pragma unroll
      for (int jj = 0; jj < 4; jj++)
        acc[i][jj] = __builtin_amdgcn_mfma_f32_16x16x32_bf16(af[i], bfr[jj], acc[i][jj], 0, 0, 0);
    __syncthreads();
  }

#pragma unroll
  for (int i = 0; i < 4; i++)
#pragma unroll
    for (int jj = 0; jj < 4; jj++)
#pragma unroll
      for (int r = 0; r < 4; r++) {
        int row = tm + wm + i * 16 + q * 4 + r;
        int col = tn + wn + jj * 16 + lr;
        float v = acc[i][jj][r];
        if (MODE == 1) {
          ((float*)Cout)[(size_t)row * N + col] = v;
        } else {
          if (row < Mv && col < Nv)
            ((float*)Cout)[(size_t)row * ldc + col] = v + bias[col];
        }
      }
}

// ---------------------------------------------------------------------------
// batched head-recombination GEMM: for z in [0,4): C[., z*128 + c] += A_z @ B_z^T
// A_z = A0 + z*sA : [M x K] bf16; B_z = B0 + z*sB : [128 x K] bf16; C f32 ldc=512
// ---------------------------------------------------------------------------
__global__ __launch_bounds__(256) void gemm_recomb(
    const bf16* __restrict__ A0, size_t sA, const bf16* __restrict__ B0, size_t sB,
    float* __restrict__ C, int K)
{
  __shared__ __attribute__((aligned(16))) bf16 As[128 * 32];
  __shared__ __attribute__((aligned(16))) bf16 Bs[128 * 32];
  const bf16* A = A0 + blockIdx.z * sA;
  const bf16* Bt = B0 + blockIdx.z * sB;
  const int tid = threadIdx.x;
  const int w = tid >> 6, l = tid & 63;
  const int tm = blockIdx.x * 128;
  const int wm = (w >> 1) * 64, wn = (w & 1) * 64;
  const int lr = l & 15, q = l >> 4;

  f32x4 acc[4][4] = {};
  const int arow = l >> 2;
  const int acol = (l & 3) * 8;
  const bf16* Ag = A + (size_t)tm * K + acol;
  const bf16* Bg = Bt + acol;

  for (int k0 = 0; k0 < K; k0 += 32) {
#pragma unroll
    for (int i = 0; i < 2; i++) {
      int rb = __builtin_amdgcn_readfirstlane(16 * (2 * w + i));
      GLOAD_LDS16(Ag + (size_t)(rb + arow) * K + k0, As + rb * 32);
      GLOAD_LDS16(Bg + (size_t)(rb + arow) * K + k0, Bs + rb * 32);
    }
    __syncthreads();
    bf16x8 af[4], bfr[4];
#pragma unroll
    for (int i = 0; i < 4; i++)
      af[i] = *(const bf16x8*)&As[(wm + i * 16 + lr) * 32 + q * 8];
#pragma unroll
    for (int jj = 0; jj < 4; jj++)
      bfr[jj] = *(const bf16x8*)&Bs[(wn + jj * 16 + lr) * 32 + q * 8];
#pragma unroll
    for (int i = 0; i < 4; i++)
#pragma unroll
      for (int jj = 0; jj < 4; jj++)
        acc[i][jj] = __builtin_amdgcn_mfma_f32_16x16x32_bf16(af[i], bfr[jj], acc[i][jj], 0, 0, 0);
    __syncthreads();
  }

#pragma unroll
  for (int i = 0; i < 4; i++)
#pragma unroll
    for (int jj = 0; jj < 4; jj++)
#pragma unroll
      for (int r = 0; r < 4; r++) {
        int row = tm + wm + i * 16 + q * 4 + r;
        int col = blockIdx.z * 128 + wn + jj * 16 + lr;
        C[(size_t)row * 512 + col] += acc[i][jj][r];
      }
}

// ---------------------------------------------------------------------------
__global__ void cast_pad_k(const float* __restrict__ src, bf16* __restrict__ dst,
                           long nvalid, long ntot)
{
  long i = ((long)blockIdx.x * 256 + threadIdx.x) * 8;
  if (i >= ntot) return;
  bf16x8 o;
  if (i + 8 <= nvalid) {
    float4 v0 = *(const float4*)(src + i);
    float4 v1 = *(const float4*)(src + i + 4);
    o[0] = (bf16)v0.x; o[1] = (bf16)v0.y; o[2] = (bf16)v0.z; o[3] = (bf16)v0.w;
    o[4] = (bf16)v1.x; o[5] = (bf16)v1.y; o[6] = (bf16)v1.z; o[7] = (bf16)v1.w;
  } else {
#pragma unroll
    for (int t = 0; t < 8; t++)
      o[t] = (i + t < nvalid) ? (bf16)src[i + t] : (bf16)0.f;
  }
  *(bf16x8*)(dst + i) = o;
}

__global__ void transpose_cast_k(const float* __restrict__ W, bf16* __restrict__ Wt,
                                 int K, int Nsrc, int Nvalid)
{
  int n = blockIdx.y;
  int k = blockIdx.x * 256 + threadIdx.x;
  Wt[(size_t)n * K + k] = (n < Nvalid) ? (bf16)W[(size_t)k * Nsrc + n] : (bf16)0.f;
}

// Brec[h][c][j*K+k] = Wt[j*512 + h*128 + c][k]; flat i = ((h*128+c)*NREL + j)*K + k
__global__ void reorder_brec_k(const bf16* __restrict__ Wt, bf16* __restrict__ Brec, int K)
{
  int i = blockIdx.x * 256 + threadIdx.x;
  int k = i % K;
  int rest = i / K;
  int j = rest % NREL;
  int rest2 = rest / NREL;
  int c = rest2 & 127;
  int h = rest2 >> 7;
  Brec[i] = Wt[((size_t)(j * 512 + h * 128 + c)) * K + k];
}

// wvec[col][k] = sum_c W[j][k][h*128+c] * a[j][h][c]; col = j*8 + side*4 + h (<40)
__global__ void wvec_k(const float* __restrict__ W, const float* __restrict__ a_s,
                       const float* __restrict__ a_d, bf16* __restrict__ wv, int K)
{
  int k = blockIdx.x * 64 + threadIdx.x;
  int col = blockIdx.y;
  float v = 0.f;
  if (col < 40) {
    int j = col >> 3, side = (col >> 2) & 1, h = col & 3;
    const float* Wrow = W + ((size_t)j * K + k) * 512 + h * 128;
    const float* av = (side ? a_d : a_s) + (j * 4 + h) * 128;
    for (int c = 0; c < 128; c++) v += Wrow[c] * av[c];
  }
  wv[(size_t)col * K + k] = (bf16)v;
}

// ---------------------------------------------------------------------------
// CSR build
// ---------------------------------------------------------------------------
__global__ void fill_i32_k(int* __restrict__ p, int v, int n)
{
  int i = blockIdx.x * 256 + threadIdx.x;
  if (i < n) p[i] = v;
}

__global__ void hist_k(const int* __restrict__ et, const int* __restrict__ ed,
                       int* __restrict__ cnt, int E, int ndst)
{
  int e = blockIdx.x * 256 + threadIdx.x;
  if (e >= E) return;
  atomicAdd(&cnt[et[e] * ndst + ed[e]], 1);
}

__global__ void scan1_k(const int* __restrict__ in, int* __restrict__ out,
                        int* __restrict__ bsums, int n)
{
  __shared__ int sh[256];
  int t = threadIdx.x;
  int i = blockIdx.x * 256 + t;
  int v = (i < n) ? in[i] : 0;
  sh[t] = v;
  __syncthreads();
#pragma unroll
  for (int o = 1; o < 256; o <<= 1) {
    int x = 0;
    if (t >= o) x = sh[t - o];
    __syncthreads();
    if (t >= o) sh[t] += x;
    __syncthreads();
  }
  if (i < n) out[i] = sh[t] - v;
  if (t == 255) bsums[blockIdx.x] = sh[255];
}

__global__ void scan2_k(int* __restrict__ b, int n)
{
  __shared__ int sh[1024];
  int t = threadIdx.x;
  int v = (t < n) ? b[t] : 0;
  sh[t] = v;
  __syncthreads();
#pragma unroll
  for (int o = 1; o < 1024; o <<= 1) {
    int x = 0;
    if (t >= o) x = sh[t - o];
    __syncthreads();
    if (t >= o) sh[t] += x;
    __syncthreads();
  }
  if (t < n) b[t] = sh[t] - v;
}

__global__ void add_off_k(int* __restrict__ out, const int* __restrict__ bscan, int n)
{
  int i = blockIdx.x * 256 + threadIdx.x;
  if (i < n) out[i] += bscan[blockIdx.x];
}

__global__ void copy_cursor_k(int* __restrict__ off, int* __restrict__ cur, int n, int E)
{
  int i = blockIdx.x * 256 + threadIdx.x;
  if (i < n) cur[i] = off[i];
  if (i == 0) off[n] = E;
}

__global__ void scatter_k(const int* __restrict__ es, const int* __restrict__ ed,
                          const int* __restrict__ et, int* __restrict__ cur,
                          int* __restrict__ sorted_src, int E, int ndst)
{
  int e = blockIdx.x * 256 + threadIdx.x;
  if (e >= E) return;
  int pos = atomicAdd(&cur[et[e] * ndst + ed[e]], 1);
  sorted_src[pos] = es[e];
}

// ---------------------------------------------------------------------------
// x-space softmax-aggregate, LDS-GATHER version.
// grid = (ndst/4, NREL) x 256 threads; one (dst,rel) key per wave.
// Edges are processed in batches of 4: the 4 source X-rows are gathered into
// a per-wave LDS slab via global_load_lds (per-lane GLOBAL address, linear
// LDS dest) so the in-flight payload costs no VGPRs -> ~13 outstanding
// requests per wave instead of ~2. exp/den computed from the (earlier-issued)
// score loads while gathers fly; then vmcnt(0), ds_read, FMA.
// Single-pass softmax (scores are O(0.3): exp(s)/sum exp(s) == softmax).
// aggx[h][d][j*K + k] = sum_e alpha[e,h] * X[src_e][k]  (bf16 out, f32 acc)
// scoresbuf [.][128]: col j*8+h = a_s, col j*8+4+h = a_d
// ---------------------------------------------------------------------------
template <int K, int CH>   // CH = K/256  (bf16x4 chunks per lane)
__global__ __launch_bounds__(256) void agg_x_k(
    const int* __restrict__ sorted_src, const int* __restrict__ off,
    const float* __restrict__ scoresbuf, const bf16* __restrict__ X,
    bf16* __restrict__ aggx, int ndst, int nrows)
{
  // per-wave slab: 4 edge rows of K bf16 each; 4 waves per block
  __shared__ __attribute__((aligned(16))) bf16 lds[4 * 4 * K];
  const int wv = threadIdx.x >> 6;
  const int l  = threadIdx.x & 63;
  const int d  = blockIdx.x * 4 + wv;
  const int j  = blockIdx.y;
  if (d >= ndst) return;
  const int key = j * ndst + d;
  const int beg = off[key], end = off[key + 1];
  const float4 svd = *(const float4*)(scoresbuf + (size_t)d * 128 + j * 8 + 4);
  const int lane_off = l * (CH * 4);
  const int slab0 = wv * (4 * K);

  float den[4] = {0.f, 0.f, 0.f, 0.f};
  f32x4 acc[4][CH] = {};

  for (int p = beg; p < end; p += 4) {
    const int rem = end - p;  // >=1; use min(rem,4) edges this batch
    int s[4];
    float4 sv[4];
#pragma unroll
    for (int i = 0; i < 4; i++)
      if (i < rem) s[i] = sorted_src[p + i];
    // score loads first (so the exp-wait leaves the gathers outstanding)
#pragma unroll
    for (int i = 0; i < 4; i++)
      if (i < rem) sv[i] = *(const float4*)(scoresbuf + (size_t)s[i] * 128 + j * 8);
    // X-row gathers into LDS (payload bypasses VGPRs)
#pragma unroll
    for (int i = 0; i < 4; i++) {
      if (i < rem) {
        const bf16* row = X + (size_t)s[i] * K;
        int ofs = __builtin_amdgcn_readfirstlane(slab0 + i * K);
        GLOAD_LDS16(row + l * 8, &lds[ofs]);          // bytes [0,1024)
        if (K == 768)
          GLOAD_LDS16(row + 256 + l * 8, &lds[ofs + 256]);  // bytes [512,1536)
      }
    }
    // softmax weights while gathers are in flight
    float e[4][4];
#pragma unroll
    for (int i = 0; i < 4; i++) {
      if (i < rem) {
        float v[4] = {sv[i].x + svd.x, sv[i].y + svd.y, sv[i].z + svd.z, sv[i].w + svd.w};
#pragma unroll
        for (int h = 0; h < 4; h++) {
          float sc = v[h] > 0.f ? v[h] : 0.2f * v[h];
          e[i][h] = __expf(sc);
          den[h] += e[i][h];
        }
      }
    }
    asm volatile("s_waitcnt vmcnt(0)" ::: "memory");
    // accumulate the batch from LDS
#pragma unroll
    for (int i = 0; i < 4; i++) {
      if (i < rem) {
        const bf16* xr = &lds[slab0 + i * K + lane_off];
        f32x4 xf[CH];
#pragma unroll
        for (int c = 0; c < CH; c++) {
          bf16x4 xv = *(const bf16x4*)(xr + c * 4);
#pragma unroll
          for (int t = 0; t < 4; t++) xf[c][t] = (float)xv[t];
        }
#pragma unroll
        for (int h = 0; h < 4; h++)
#pragma unroll
          for (int c = 0; c < CH; c++)
            acc[h][c] += e[i][h] * xf[c];
      }
    }
  }

#pragma unroll
  for (int h = 0; h < 4; h++) {
    float sc = 1.f / fmaxf(den[h], 1e-16f);
    bf16* orow = aggx + ((size_t)h * nrows + d) * ((size_t)NREL * K) + (size_t)j * K + lane_off;
#pragma unroll
    for (int c = 0; c < CH; c++) {
      bf16x4 o;
#pragma unroll
      for (int t = 0; t < 4; t++) o[t] = (bf16)(acc[h][c][t] * sc);
      *(bf16x4*)(orow + c * 4) = o;
    }
  }
}

// ---------------------------------------------------------------------------
__global__ void bias_combine_k(const float* __restrict__ bsk, const float* __restrict__ brel,
                               float* __restrict__ out, int R)
{
  int c = blockIdx.x * 256 + threadIdx.x;
  if (c >= HID) return;
  float v = bsk[c];
  for (int j = 0; j < R; j++) v += brel[j * HID + c];
  out[c] = v;
}

__global__ void fill_f32_k(float* __restrict__ p, float v, int n)
{
  int i = blockIdx.x * 256 + threadIdx.x;
  if (i < n) p[i] = v;
}

__global__ void bn_stats_k(const float* __restrict__ X, const float* __restrict__ bias,
                           float* __restrict__ sums, float* __restrict__ sumsq, int rows)
{
  int t = threadIdx.x;
  int c0 = t * 2;
  float b0 = bias[c0], b1 = bias[c0 + 1];
  float s0 = 0, s1 = 0, q0 = 0, q1 = 0;
  for (int r = blockIdx.x; r < rows; r += gridDim.x) {
    float2 v = *(const float2*)(X + (size_t)r * HID + c0);
    float v0 = v.x + b0, v1 = v.y + b1;
    s0 += v0; q0 += v0 * v0;
    s1 += v1; q1 += v1 * v1;
  }
  atomicAdd(sums + c0, s0); atomicAdd(sums + c0 + 1, s1);
  atomicAdd(sumsq + c0, q0); atomicAdd(sumsq + c0 + 1, q1);
}

template <int ACT>
__global__ void bn_apply_k(const float* __restrict__ X, const float* __restrict__ bias,
                           const float* __restrict__ sums, const float* __restrict__ sumsq,
                           const float* __restrict__ gamma, const float* __restrict__ beta,
                           bf16* __restrict__ Y, int rows, float invN)
{
  int idx = blockIdx.x * 256 + threadIdx.x;
  int row = idx >> 9, c = idx & 511;
  float y = 0.f;
  if (row < rows) {
    float mu = sums[c] * invN;
    float var = sumsq[c] * invN - mu * mu;
    float v = X[idx] + bias[c];
    float xn = (v - mu) * rsqrtf(var + 1e-5f);
    y = gamma[c] * xn + beta[c];
    y = (ACT == 0) ? (y > 0.f ? y : expm1f(y)) : fmaxf(y, 0.f);
  }
  Y[idx] = (bf16)y;
}

// ---------------------------------------------------------------------------
extern "C" void kernel_launch(void* const* d_in, const int* in_sizes, int n_in,
                              void* d_out, int out_size, void* d_ws, size_t ws_size,
                              hipStream_t stream)
{
  const float* x    = (const float*)d_in[0];
  const int*   es0  = (const int*)d_in[1];
  const int*   ed0  = (const int*)d_in[2];
  const int*   et0  = (const int*)d_in[3];
  const int*   es1  = (const int*)d_in[4];
  const int*   ed1  = (const int*)d_in[5];
  const int*   et1  = (const int*)d_in[6];
  const float* W0   = (const float*)d_in[7];
  const float* as0  = (const float*)d_in[8];
  const float* ad0  = (const float*)d_in[9];
  const float* b0   = (const float*)d_in[10];
  const float* Wsk0 = (const float*)d_in[11];
  const float* bsk0 = (const float*)d_in[12];
  const float* g0   = (const float*)d_in[13];
  const float* be0  = (const float*)d_in[14];
  const float* W1   = (const float*)d_in[15];
  const float* as1  = (const float*)d_in[16];
  const float* ad1  = (const float*)d_in[17];
  const float* b1   = (const float*)d_in[18];
  const float* Wsk1 = (const float*)d_in[19];
  const float* bsk1 = (const float*)d_in[20];
  const float* g1   = (const float*)d_in[21];
  const float* be1  = (const float*)d_in[22];
  const float* Wm1  = (const float*)d_in[23];
  const float* bm1  = (const float*)d_in[24];
  const float* gm   = (const float*)d_in[25];
  const float* bmn  = (const float*)d_in[26];
  const float* Wm2  = (const float*)d_in[27];
  const float* bm2  = (const float*)d_in[28];

  char* wsb = (char*)d_ws;
  size_t off = 0;
  auto alloc = [&](size_t bytes) -> char* {
    char* p = wsb + off;
    off = (off + bytes + 255) & ~(size_t)255;
    return p;
  };
  // persistent / small
  bf16*  Wsk0t  = (bf16*)alloc((size_t)HID * K0 * 2);
  bf16*  Wsk1t  = (bf16*)alloc((size_t)HID * HID * 2);
  bf16*  Wm1t   = (bf16*)alloc((size_t)HID * HID * 2);
  bf16*  Wm2t   = (bf16*)alloc((size_t)OUTP * HID * 2);
  bf16*  W0t    = (bf16*)alloc((size_t)NREL * HID * K0 * 2);
  bf16*  W1t    = (bf16*)alloc((size_t)NREL * HID * HID * 2);
  bf16*  Brec0  = (bf16*)alloc((size_t)4 * 128 * NREL * K0 * 2);
  bf16*  Brec1  = (bf16*)alloc((size_t)4 * 128 * NREL * HID * 2);
  bf16*  wvec0  = (bf16*)alloc((size_t)128 * K0 * 2);
  bf16*  wvec1  = (bf16*)alloc((size_t)128 * HID * 2);
  float* biasb  = (float*)alloc(HID * 4);
  float* statsb = (float*)alloc(1024 * 4);
  int*   offb   = (int*)alloc((size_t)(NREL * N1 + 1) * 4);
  int*   curb   = (int*)alloc((size_t)NREL * N1 * 4);
  int*   bsumsb = (int*)alloc(1024 * 4);
  int*   srtb   = (int*)alloc((size_t)E0 * 4);
  float* out0   = (float*)alloc((size_t)N1P * HID * 4);
  bf16*  h1b    = (bf16*)alloc((size_t)N1P * HID * 2);
  bf16*  h2b    = (bf16*)alloc((size_t)N2P * HID * 2);
  bf16*  zbb    = (bf16*)alloc((size_t)N2P * HID * 2);
  float* out1   = (float*)alloc((size_t)N2P * HID * 4);
  float* zf     = (float*)alloc((size_t)N2P * HID * 4);
  // big regions
  bf16*  xb        = (bf16*)alloc((size_t)M0P * K0 * 2);
  float* scoresbuf = (float*)alloc((size_t)M0P * 128 * 4);
  bf16*  aggx      = (bf16*)alloc((size_t)4 * N1P * NREL * K0 * 2);  // reused for layer 1

  auto build_csr = [&](const int* es, const int* ed, const int* et, int E, int ndst) {
    int nkeys = NREL * ndst;
    int nbE = (E + 255) / 256;
    int nbK = (nkeys + 255) / 256;
    fill_i32_k<<<nbK, 256, 0, stream>>>(curb, 0, nkeys);
    hist_k<<<nbE, 256, 0, stream>>>(et, ed, curb, E, ndst);
    scan1_k<<<nbK, 256, 0, stream>>>(curb, offb, bsumsb, nkeys);
    scan2_k<<<1, 1024, 0, stream>>>(bsumsb, nbK);
    add_off_k<<<nbK, 256, 0, stream>>>(offb, bsumsb, nkeys);
    copy_cursor_k<<<nbK, 256, 0, stream>>>(offb, curb, nkeys, E);
    scatter_k<<<nbE, 256, 0, stream>>>(es, ed, et, curb, srtb, E, ndst);
  };

  // ---- weight prep ----
  cast_pad_k<<<((size_t)M0P * K0 / 8 + 255) / 256, 256, 0, stream>>>(
      x, xb, (long)M0 * K0, (long)M0P * K0);
  for (int j = 0; j < NREL; j++)
    transpose_cast_k<<<dim3(3, 512), 256, 0, stream>>>(
        W0 + (size_t)j * K0 * HID, W0t + (size_t)j * HID * K0, K0, HID, HID);
  transpose_cast_k<<<dim3(3, 512), 256, 0, stream>>>(Wsk0, Wsk0t, K0, HID, HID);
  for (int j = 0; j < NREL; j++)
    transpose_cast_k<<<dim3(2, 512), 256, 0, stream>>>(
        W1 + (size_t)j * HID * HID, W1t + (size_t)j * HID * HID, HID, HID, HID);
  transpose_cast_k<<<dim3(2, 512), 256, 0, stream>>>(Wsk1, Wsk1t, HID, HID, HID);
  transpose_cast_k<<<dim3(2, 512), 256, 0, stream>>>(Wm1, Wm1t, HID, HID, HID);
  transpose_cast_k<<<dim3(2, OUTP), 256, 0, stream>>>(Wm2, Wm2t, HID, OUTC, OUTC);
  reorder_brec_k<<<(4 * 128 * NREL * K0) / 256, 256, 0, stream>>>(W0t, Brec0, K0);
  reorder_brec_k<<<(4 * 128 * NREL * HID) / 256, 256, 0, stream>>>(W1t, Brec1, HID);
  wvec_k<<<dim3(K0 / 64, 128), 64, 0, stream>>>(W0, as0, ad0, wvec0, K0);
  wvec_k<<<dim3(HID / 64, 128), 64, 0, stream>>>(W1, as1, ad1, wvec1, HID);

  // ---- layer 0 ----
  {
    const int KT = NREL * K0;  // 3840
    build_csr(es0, ed0, et0, E0, N1);
    gemm_bt<1><<<dim3(M0P / 128, 1), 256, 0, stream>>>(xb, wvec0, scoresbuf, 128, K0, 0, 0, 0, nullptr);
    gemm_bt<1><<<dim3(N1P / 128, 4), 256, 0, stream>>>(xb, Wsk0t, out0, HID, K0, 0, 0, 0, nullptr);
    // zero pad rows of aggx (d in [N1, N1P))
    for (int h = 0; h < 4; h++)
      fill_i32_k<<<((N1P - N1) * KT * 2 / 4 + 255) / 256, 256, 0, stream>>>(
          (int*)(aggx + ((size_t)h * N1P + N1) * KT), 0, (N1P - N1) * KT / 2);
    agg_x_k<K0, K0 / 256><<<dim3(N1 / 4, NREL), 256, 0, stream>>>(
        srtb, offb, scoresbuf, xb, aggx, N1, N1P);
    gemm_recomb<<<dim3(N1P / 128, 1, 4), 256, 0, stream>>>(
        aggx, (size_t)N1P * KT, Brec0, (size_t)128 * KT, out0, KT);
    bias_combine_k<<<2, 256, 0, stream>>>(bsk0, b0, biasb, NREL);
    fill_f32_k<<<4, 256, 0, stream>>>(statsb, 0.f, 1024);
    bn_stats_k<<<256, 256, 0, stream>>>(out0, biasb, statsb, statsb + 512, N1);
    bn_apply_k<0><<<(N1P * HID) / 256, 256, 0, stream>>>(out0, biasb, statsb, statsb + 512,
                                                         g0, be0, h1b, N1, 1.f / N1);
  }

  // ---- layer 1 ----
  {
    const int KT = NREL * HID;  // 2560
    build_csr(es1, ed1, et1, E1, N2);
    gemm_bt<1><<<dim3(N1P / 128, 1), 256, 0, stream>>>(h1b, wvec1, scoresbuf, 128, HID, 0, 0, 0, nullptr);
    gemm_bt<1><<<dim3(N2P / 128, 4), 256, 0, stream>>>(h1b, Wsk1t, out1, HID, HID, 0, 0, 0, nullptr);
    for (int h = 0; h < 4; h++)
      fill_i32_k<<<((N2P - N2) * KT * 2 / 4 + 255) / 256, 256, 0, stream>>>(
          (int*)(aggx + ((size_t)h * N2P + N2) * KT), 0, (N2P - N2) * KT / 2);
    agg_x_k<HID, HID / 256><<<dim3(N2 / 4, NREL), 256, 0, stream>>>(
        srtb, offb, scoresbuf, h1b, aggx, N2, N2P);
    gemm_recomb<<<dim3(N2P / 128, 1, 4), 256, 0, stream>>>(
        aggx, (size_t)N2P * KT, Brec1, (size_t)128 * KT, out1, KT);
    bias_combine_k<<<2, 256, 0, stream>>>(bsk1, b1, biasb, NREL);
    fill_f32_k<<<4, 256, 0, stream>>>(statsb, 0.f, 1024);
    bn_stats_k<<<256, 256, 0, stream>>>(out1, biasb, statsb, statsb + 512, N2);
    bn_apply_k<0><<<(N2P * HID) / 256, 256, 0, stream>>>(out1, biasb, statsb, statsb + 512,
                                                         g1, be1, h2b, N2, 1.f / N2);
  }

  // ---- MLP head ----
  gemm_bt<1><<<dim3(N2P / 128, 4), 256, 0, stream>>>(h2b, Wm1t, zf, HID, HID, 0, 0, 0, nullptr);
  fill_f32_k<<<4, 256, 0, stream>>>(statsb, 0.f, 1024);
  bn_stats_k<<<256, 256, 0, stream>>>(zf, bm1, statsb, statsb + 512, N2);
  bn_apply_k<1><<<(N2P * HID) / 256, 256, 0, stream>>>(zf, bm1, statsb, statsb + 512,
                                                       gm, bmn, zbb, N2, 1.f / N2);
  gemm_bt<2><<<dim3(N2P / 128, OUTP / 128), 256, 0, stream>>>(
      zbb, Wm2t, d_out, OUTP, HID, N2, OUTC, OUTC, bm2);

  (void)in_sizes; (void)n_in; (void)out_size; (void)ws_size;
}

// Round 5
// 2013.690 us; speedup vs baseline: 1.0010x; 1.0010x over previous
//
#include <hip/hip_runtime.h>
#include <math.h>

typedef __bf16 bf16;
typedef __bf16 bf16x4 __attribute__((ext_vector_type(4)));
typedef __bf16 bf16x8 __attribute__((ext_vector_type(8)));
typedef float f32x4 __attribute__((ext_vector_type(4)));

#define M0   120000
#define M0P  120064   // 938*128
#define K0   768
#define HID  512
#define NREL 5
#define N1   30000
#define N1P  30080    // 235*128
#define E0   600000
#define N2   8000
#define N2P  8064     // 63*128
#define E1   150000
#define OUTC 153
#define OUTP 256

#define GLOAD_LDS16(g, s) \
  __builtin_amdgcn_global_load_lds((const __attribute__((address_space(1))) void*)(g), \
                                   (__attribute__((address_space(3))) void*)(s), 16, 0, 0)

// ---------------------------------------------------------------------------
// GEMM: C[M x N] = A[M x K](bf16 rm) * Bt[N x K](bf16 rm)^T
// MODE 1: store f32, ldc=N. MODE 2: f32+bias, guarded, ldc param.
// ---------------------------------------------------------------------------
template <int MODE>
__global__ __launch_bounds__(256) void gemm_bt(
    const bf16* __restrict__ A, const bf16* __restrict__ Bt, void* __restrict__ Cout,
    int N, int K, int Mv, int Nv, int ldc, const float* __restrict__ bias)
{
  __shared__ __attribute__((aligned(16))) bf16 As[128 * 32];
  __shared__ __attribute__((aligned(16))) bf16 Bs[128 * 32];
  const int tid = threadIdx.x;
  const int w = tid >> 6, l = tid & 63;
  const int tm = blockIdx.x * 128, tn = blockIdx.y * 128;
  const int wm = (w >> 1) * 64, wn = (w & 1) * 64;
  const int lr = l & 15, q = l >> 4;

  f32x4 acc[4][4] = {};

  const int arow = l >> 2;
  const int acol = (l & 3) * 8;
  const bf16* Ag = A + (size_t)tm * K + acol;
  const bf16* Bg = Bt + (size_t)tn * K + acol;

  for (int k0 = 0; k0 < K; k0 += 32) {
#pragma unroll
    for (int i = 0; i < 2; i++) {
      int rb = __builtin_amdgcn_readfirstlane(16 * (2 * w + i));
      GLOAD_LDS16(Ag + (size_t)(rb + arow) * K + k0, As + rb * 32);
      GLOAD_LDS16(Bg + (size_t)(rb + arow) * K + k0, Bs + rb * 32);
    }
    __syncthreads();
    bf16x8 af[4], bfr[4];
#pragma unroll
    for (int i = 0; i < 4; i++)
      af[i] = *(const bf16x8*)&As[(wm + i * 16 + lr) * 32 + q * 8];
#pragma unroll
    for (int jj = 0; jj < 4; jj++)
      bfr[jj] = *(const bf16x8*)&Bs[(wn + jj * 16 + lr) * 32 + q * 8];
#pragma unroll
    for (int i = 0; i < 4; i++)
#pragma unroll
      for (int jj = 0; jj < 4; jj++)
        acc[i][jj] = __builtin_amdgcn_mfma_f32_16x16x32_bf16(af[i], bfr[jj], acc[i][jj], 0, 0, 0);
    __syncthreads();
  }

#pragma unroll
  for (int i = 0; i < 4; i++)
#pragma unroll
    for (int jj = 0; jj < 4; jj++)
#pragma unroll
      for (int r = 0; r < 4; r++) {
        int row = tm + wm + i * 16 + q * 4 + r;
        int col = tn + wn + jj * 16 + lr;
        float v = acc[i][jj][r];
        if (MODE == 1) {
          ((float*)Cout)[(size_t)row * N + col] = v;
        } else {
          if (row < Mv && col < Nv)
            ((float*)Cout)[(size_t)row * ldc + col] = v + bias[col];
        }
      }
}

// ---------------------------------------------------------------------------
// batched head-recombination GEMM: for z in [0,4): C[., z*128 + c] += A_z @ B_z^T
// A_z = A0 + z*sA : [M x K] bf16; B_z = B0 + z*sB : [128 x K] bf16; C f32 ldc=512
// ---------------------------------------------------------------------------
__global__ __launch_bounds__(256) void gemm_recomb(
    const bf16* __restrict__ A0, size_t sA, const bf16* __restrict__ B0, size_t sB,
    float* __restrict__ C, int K)
{
  __shared__ __attribute__((aligned(16))) bf16 As[128 * 32];
  __shared__ __attribute__((aligned(16))) bf16 Bs[128 * 32];
  const bf16* A = A0 + blockIdx.z * sA;
  const bf16* Bt = B0 + blockIdx.z * sB;
  const int tid = threadIdx.x;
  const int w = tid >> 6, l = tid & 63;
  const int tm = blockIdx.x * 128;
  const int wm = (w >> 1) * 64, wn = (w & 1) * 64;
  const int lr = l & 15, q = l >> 4;

  f32x4 acc[4][4] = {};
  const int arow = l >> 2;
  const int acol = (l & 3) * 8;
  const bf16* Ag = A + (size_t)tm * K + acol;
  const bf16* Bg = Bt + acol;

  for (int k0 = 0; k0 < K; k0 += 32) {
#pragma unroll
    for (int i = 0; i < 2; i++) {
      int rb = __builtin_amdgcn_readfirstlane(16 * (2 * w + i));
      GLOAD_LDS16(Ag + (size_t)(rb + arow) * K + k0, As + rb * 32);
      GLOAD_LDS16(Bg + (size_t)(rb + arow) * K + k0, Bs + rb * 32);
    }
    __syncthreads();
    bf16x8 af[4], bfr[4];
#pragma unroll
    for (int i = 0; i < 4; i++)
      af[i] = *(const bf16x8*)&As[(wm + i * 16 + lr) * 32 + q * 8];
#pragma unroll
    for (int jj = 0; jj < 4; jj++)
      bfr[jj] = *(const bf16x8*)&Bs[(wn + jj * 16 + lr) * 32 + q * 8];
#pragma unroll
    for (int i = 0; i < 4; i++)
#pragma unroll
      for (int jj = 0; jj < 4; jj++)
        acc[i][jj] = __builtin_amdgcn_mfma_f32_16x16x32_bf16(af[i], bfr[jj], acc[i][jj], 0, 0, 0);
    __syncthreads();
  }

#pragma unroll
  for (int i = 0; i < 4; i++)
#pragma unroll
    for (int jj = 0; jj < 4; jj++)
#pragma unroll
      for (int r = 0; r < 4; r++) {
        int row = tm + wm + i * 16 + q * 4 + r;
        int col = blockIdx.z * 128 + wn + jj * 16 + lr;
        C[(size_t)row * 512 + col] += acc[i][jj][r];
      }
}

// ---------------------------------------------------------------------------
__global__ void cast_pad_k(const float* __restrict__ src, bf16* __restrict__ dst,
                           long nvalid, long ntot)
{
  long i = ((long)blockIdx.x * 256 + threadIdx.x) * 8;
  if (i >= ntot) return;
  bf16x8 o;
  if (i + 8 <= nvalid) {
    float4 v0 = *(const float4*)(src + i);
    float4 v1 = *(const float4*)(src + i + 4);
    o[0] = (bf16)v0.x; o[1] = (bf16)v0.y; o[2] = (bf16)v0.z; o[3] = (bf16)v0.w;
    o[4] = (bf16)v1.x; o[5] = (bf16)v1.y; o[6] = (bf16)v1.z; o[7] = (bf16)v1.w;
  } else {
#pragma unroll
    for (int t = 0; t < 8; t++)
      o[t] = (i + t < nvalid) ? (bf16)src[i + t] : (bf16)0.f;
  }
  *(bf16x8*)(dst + i) = o;
}

__global__ void transpose_cast_k(const float* __restrict__ W, bf16* __restrict__ Wt,
                                 int K, int Nsrc, int Nvalid)
{
  int n = blockIdx.y;
  int k = blockIdx.x * 256 + threadIdx.x;
  Wt[(size_t)n * K + k] = (n < Nvalid) ? (bf16)W[(size_t)k * Nsrc + n] : (bf16)0.f;
}

// Brec[h][c][j*K+k] = Wt[j*512 + h*128 + c][k]; flat i = ((h*128+c)*NREL + j)*K + k
__global__ void reorder_brec_k(const bf16* __restrict__ Wt, bf16* __restrict__ Brec, int K)
{
  int i = blockIdx.x * 256 + threadIdx.x;
  int k = i % K;
  int rest = i / K;
  int j = rest % NREL;
  int rest2 = rest / NREL;
  int c = rest2 & 127;
  int h = rest2 >> 7;
  Brec[i] = Wt[((size_t)(j * 512 + h * 128 + c)) * K + k];
}

// wvec[col][k] = sum_c W[j][k][h*128+c] * a[j][h][c]; col = j*8 + side*4 + h (<40)
__global__ void wvec_k(const float* __restrict__ W, const float* __restrict__ a_s,
                       const float* __restrict__ a_d, bf16* __restrict__ wv, int K)
{
  int k = blockIdx.x * 64 + threadIdx.x;
  int col = blockIdx.y;
  float v = 0.f;
  if (col < 40) {
    int j = col >> 3, side = (col >> 2) & 1, h = col & 3;
    const float* Wrow = W + ((size_t)j * K + k) * 512 + h * 128;
    const float* av = (side ? a_d : a_s) + (j * 4 + h) * 128;
    for (int c = 0; c < 128; c++) v += Wrow[c] * av[c];
  }
  wv[(size_t)col * K + k] = (bf16)v;
}

// ---------------------------------------------------------------------------
// CSR build
// ---------------------------------------------------------------------------
__global__ void fill_i32_k(int* __restrict__ p, int v, int n)
{
  int i = blockIdx.x * 256 + threadIdx.x;
  if (i < n) p[i] = v;
}

__global__ void hist_k(const int* __restrict__ et, const int* __restrict__ ed,
                       int* __restrict__ cnt, int E, int ndst)
{
  int e = blockIdx.x * 256 + threadIdx.x;
  if (e >= E) return;
  atomicAdd(&cnt[et[e] * ndst + ed[e]], 1);
}

__global__ void scan1_k(const int* __restrict__ in, int* __restrict__ out,
                        int* __restrict__ bsums, int n)
{
  __shared__ int sh[256];
  int t = threadIdx.x;
  int i = blockIdx.x * 256 + t;
  int v = (i < n) ? in[i] : 0;
  sh[t] = v;
  __syncthreads();
#pragma unroll
  for (int o = 1; o < 256; o <<= 1) {
    int x = 0;
    if (t >= o) x = sh[t - o];
    __syncthreads();
    if (t >= o) sh[t] += x;
    __syncthreads();
  }
  if (i < n) out[i] = sh[t] - v;
  if (t == 255) bsums[blockIdx.x] = sh[255];
}

__global__ void scan2_k(int* __restrict__ b, int n)
{
  __shared__ int sh[1024];
  int t = threadIdx.x;
  int v = (t < n) ? b[t] : 0;
  sh[t] = v;
  __syncthreads();
#pragma unroll
  for (int o = 1; o < 1024; o <<= 1) {
    int x = 0;
    if (t >= o) x = sh[t - o];
    __syncthreads();
    if (t >= o) sh[t] += x;
    __syncthreads();
  }
  if (t < n) b[t] = sh[t] - v;
}

__global__ void add_off_k(int* __restrict__ out, const int* __restrict__ bscan, int n)
{
  int i = blockIdx.x * 256 + threadIdx.x;
  if (i < n) out[i] += bscan[blockIdx.x];
}

__global__ void copy_cursor_k(int* __restrict__ off, int* __restrict__ cur, int n, int E)
{
  int i = blockIdx.x * 256 + threadIdx.x;
  if (i < n) cur[i] = off[i];
  if (i == 0) off[n] = E;
}

__global__ void scatter_k(const int* __restrict__ es, const int* __restrict__ ed,
                          const int* __restrict__ et, int* __restrict__ cur,
                          int* __restrict__ sorted_src, int E, int ndst)
{
  int e = blockIdx.x * 256 + threadIdx.x;
  if (e >= E) return;
  int pos = atomicAdd(&cur[et[e] * ndst + ed[e]], 1);
  sorted_src[pos] = es[e];
}

// ---------------------------------------------------------------------------
// x-space softmax-aggregate, DUAL-KEY software-pipelined version.
// grid = (ndst/8, NREL) x 256 threads; each wave owns TWO adjacent dst keys
// (d0, d0+1) for one relation -> two INDEPENDENT gather chains interleaved in
// registers (while A's X-row load is in flight, B issues/consumes, and vice
// versa). Source ids fetched 2 ahead, payloads 1 ahead, so the id->payload
// dependency is off the critical path. All branch conditions are wave-uniform.
// Single-pass softmax (scores are O(0.3): exp(s)/sum exp(s) == softmax).
// aggx[h][d][j*K + k] = sum_e alpha[e,h] * X[src_e][k]  (bf16 out, f32 acc)
// scoresbuf [.][128]: col j*8+h = a_s, col j*8+4+h = a_d
// ---------------------------------------------------------------------------
template <int K, int CH>   // CH = K/256  (bf16x4 chunks per lane)
__global__ __launch_bounds__(256) void agg_x_k(
    const int* __restrict__ sorted_src, const int* __restrict__ off,
    const float* __restrict__ scoresbuf, const bf16* __restrict__ X,
    bf16* __restrict__ aggx, int ndst, int nrows)
{
  const int wv = threadIdx.x >> 6;
  const int l  = threadIdx.x & 63;
  const int d0 = blockIdx.x * 8 + wv * 2;
  const int j  = blockIdx.y;
  if (d0 + 1 >= ndst) return;          // ndst divisible by 8 here; guard anyway
  const int base = j * ndst + d0;
  int pA = off[base];
  const int endA = off[base + 1];
  int pB = endA;                        // adjacent key ranges are contiguous
  const int endB = off[base + 2];
  const int lane_off = l * (CH * 4);

  const float4 svdA = *(const float4*)(scoresbuf + (size_t)d0 * 128 + j * 8 + 4);
  const float4 svdB = *(const float4*)(scoresbuf + (size_t)(d0 + 1) * 128 + j * 8 + 4);

  float denA[4] = {0.f, 0.f, 0.f, 0.f}, denB[4] = {0.f, 0.f, 0.f, 0.f};
  f32x4 accA[4][CH] = {}, accB[4][CH] = {};

  // pipeline state: payload of edge p, id of edge p+1
  int sA1 = 0, sB1 = 0;
  float4 svA0, svB0;
  bf16x4 xvA0[CH], xvB0[CH];

  bool mA = pA < endA, mB = pB < endB;
  if (mA) {
    int s0 = sorted_src[pA];
    if (pA + 1 < endA) sA1 = sorted_src[pA + 1];
    svA0 = *(const float4*)(scoresbuf + (size_t)s0 * 128 + j * 8);
    const bf16* xr = X + (size_t)s0 * K + lane_off;
#pragma unroll
    for (int c = 0; c < CH; c++) xvA0[c] = *(const bf16x4*)(xr + c * 4);
  }
  if (mB) {
    int s0 = sorted_src[pB];
    if (pB + 1 < endB) sB1 = sorted_src[pB + 1];
    svB0 = *(const float4*)(scoresbuf + (size_t)s0 * 128 + j * 8);
    const bf16* xr = X + (size_t)s0 * K + lane_off;
#pragma unroll
    for (int c = 0; c < CH; c++) xvB0[c] = *(const bf16x4*)(xr + c * 4);
  }

  while (mA || mB) {
    const bool moreA = mA && (pA + 1 < endA);
    const bool moreB = mB && (pB + 1 < endB);
    float4 svA1, svB1;
    bf16x4 xvA1[CH], xvB1[CH];
    int sA2 = 0, sB2 = 0;
    // issue both pipelines' prefetches before either consume
    if (moreA) {
      svA1 = *(const float4*)(scoresbuf + (size_t)sA1 * 128 + j * 8);
      const bf16* xr = X + (size_t)sA1 * K + lane_off;
#pragma unroll
      for (int c = 0; c < CH; c++) xvA1[c] = *(const bf16x4*)(xr + c * 4);
      if (pA + 2 < endA) sA2 = sorted_src[pA + 2];
    }
    if (moreB) {
      svB1 = *(const float4*)(scoresbuf + (size_t)sB1 * 128 + j * 8);
      const bf16* xr = X + (size_t)sB1 * K + lane_off;
#pragma unroll
      for (int c = 0; c < CH; c++) xvB1[c] = *(const bf16x4*)(xr + c * 4);
      if (pB + 2 < endB) sB2 = sorted_src[pB + 2];
    }
    // consume A's current edge
    if (mA) {
      float v[4] = {svA0.x + svdA.x, svA0.y + svdA.y, svA0.z + svdA.z, svA0.w + svdA.w};
      float e[4];
#pragma unroll
      for (int h = 0; h < 4; h++) {
        float sc = v[h] > 0.f ? v[h] : 0.2f * v[h];
        e[h] = __expf(sc);
        denA[h] += e[h];
      }
      f32x4 xf[CH];
#pragma unroll
      for (int c = 0; c < CH; c++) {
#pragma unroll
        for (int t = 0; t < 4; t++) xf[c][t] = (float)xvA0[c][t];
      }
#pragma unroll
      for (int h = 0; h < 4; h++)
#pragma unroll
        for (int c = 0; c < CH; c++)
          accA[h][c] += e[h] * xf[c];
      pA++;
      if (moreA) {
        svA0 = svA1; sA1 = sA2;
#pragma unroll
        for (int c = 0; c < CH; c++) xvA0[c] = xvA1[c];
      }
      mA = pA < endA;
    }
    // consume B's current edge
    if (mB) {
      float v[4] = {svB0.x + svdB.x, svB0.y + svdB.y, svB0.z + svdB.z, svB0.w + svdB.w};
      float e[4];
#pragma unroll
      for (int h = 0; h < 4; h++) {
        float sc = v[h] > 0.f ? v[h] : 0.2f * v[h];
        e[h] = __expf(sc);
        denB[h] += e[h];
      }
      f32x4 xf[CH];
#pragma unroll
      for (int c = 0; c < CH; c++) {
#pragma unroll
        for (int t = 0; t < 4; t++) xf[c][t] = (float)xvB0[c][t];
      }
#pragma unroll
      for (int h = 0; h < 4; h++)
#pragma unroll
        for (int c = 0; c < CH; c++)
          accB[h][c] += e[h] * xf[c];
      pB++;
      if (moreB) {
        svB0 = svB1; sB1 = sB2;
#pragma unroll
        for (int c = 0; c < CH; c++) xvB0[c] = xvB1[c];
      }
      mB = pB < endB;
    }
  }

#pragma unroll
  for (int h = 0; h < 4; h++) {
    float scA = 1.f / fmaxf(denA[h], 1e-16f);
    float scB = 1.f / fmaxf(denB[h], 1e-16f);
    bf16* orowA = aggx + ((size_t)h * nrows + d0) * ((size_t)NREL * K) + (size_t)j * K + lane_off;
    bf16* orowB = aggx + ((size_t)h * nrows + d0 + 1) * ((size_t)NREL * K) + (size_t)j * K + lane_off;
#pragma unroll
    for (int c = 0; c < CH; c++) {
      bf16x4 oA, oB;
#pragma unroll
      for (int t = 0; t < 4; t++) {
        oA[t] = (bf16)(accA[h][c][t] * scA);
        oB[t] = (bf16)(accB[h][c][t] * scB);
      }
      *(bf16x4*)(orowA + c * 4) = oA;
      *(bf16x4*)(orowB + c * 4) = oB;
    }
  }
}

// ---------------------------------------------------------------------------
__global__ void bias_combine_k(const float* __restrict__ bsk, const float* __restrict__ brel,
                               float* __restrict__ out, int R)
{
  int c = blockIdx.x * 256 + threadIdx.x;
  if (c >= HID) return;
  float v = bsk[c];
  for (int j = 0; j < R; j++) v += brel[j * HID + c];
  out[c] = v;
}

__global__ void fill_f32_k(float* __restrict__ p, float v, int n)
{
  int i = blockIdx.x * 256 + threadIdx.x;
  if (i < n) p[i] = v;
}

__global__ void bn_stats_k(const float* __restrict__ X, const float* __restrict__ bias,
                           float* __restrict__ sums, float* __restrict__ sumsq, int rows)
{
  int t = threadIdx.x;
  int c0 = t * 2;
  float b0 = bias[c0], b1 = bias[c0 + 1];
  float s0 = 0, s1 = 0, q0 = 0, q1 = 0;
  for (int r = blockIdx.x; r < rows; r += gridDim.x) {
    float2 v = *(const float2*)(X + (size_t)r * HID + c0);
    float v0 = v.x + b0, v1 = v.y + b1;
    s0 += v0; q0 += v0 * v0;
    s1 += v1; q1 += v1 * v1;
  }
  atomicAdd(sums + c0, s0); atomicAdd(sums + c0 + 1, s1);
  atomicAdd(sumsq + c0, q0); atomicAdd(sumsq + c0 + 1, q1);
}

template <int ACT>
__global__ void bn_apply_k(const float* __restrict__ X, const float* __restrict__ bias,
                           const float* __restrict__ sums, const float* __restrict__ sumsq,
                           const float* __restrict__ gamma, const float* __restrict__ beta,
                           bf16* __restrict__ Y, int rows, float invN)
{
  int idx = blockIdx.x * 256 + threadIdx.x;
  int row = idx >> 9, c = idx & 511;
  float y = 0.f;
  if (row < rows) {
    float mu = sums[c] * invN;
    float var = sumsq[c] * invN - mu * mu;
    float v = X[idx] + bias[c];
    float xn = (v - mu) * rsqrtf(var + 1e-5f);
    y = gamma[c] * xn + beta[c];
    y = (ACT == 0) ? (y > 0.f ? y : expm1f(y)) : fmaxf(y, 0.f);
  }
  Y[idx] = (bf16)y;
}

// ---------------------------------------------------------------------------
extern "C" void kernel_launch(void* const* d_in, const int* in_sizes, int n_in,
                              void* d_out, int out_size, void* d_ws, size_t ws_size,
                              hipStream_t stream)
{
  const float* x    = (const float*)d_in[0];
  const int*   es0  = (const int*)d_in[1];
  const int*   ed0  = (const int*)d_in[2];
  const int*   et0  = (const int*)d_in[3];
  const int*   es1  = (const int*)d_in[4];
  const int*   ed1  = (const int*)d_in[5];
  const int*   et1  = (const int*)d_in[6];
  const float* W0   = (const float*)d_in[7];
  const float* as0  = (const float*)d_in[8];
  const float* ad0  = (const float*)d_in[9];
  const float* b0   = (const float*)d_in[10];
  const float* Wsk0 = (const float*)d_in[11];
  const float* bsk0 = (const float*)d_in[12];
  const float* g0   = (const float*)d_in[13];
  const float* be0  = (const float*)d_in[14];
  const float* W1   = (const float*)d_in[15];
  const float* as1  = (const float*)d_in[16];
  const float* ad1  = (const float*)d_in[17];
  const float* b1   = (const float*)d_in[18];
  const float* Wsk1 = (const float*)d_in[19];
  const float* bsk1 = (const float*)d_in[20];
  const float* g1   = (const float*)d_in[21];
  const float* be1  = (const float*)d_in[22];
  const float* Wm1  = (const float*)d_in[23];
  const float* bm1  = (const float*)d_in[24];
  const float* gm   = (const float*)d_in[25];
  const float* bmn  = (const float*)d_in[26];
  const float* Wm2  = (const float*)d_in[27];
  const float* bm2  = (const float*)d_in[28];

  char* wsb = (char*)d_ws;
  size_t off = 0;
  auto alloc = [&](size_t bytes) -> char* {
    char* p = wsb + off;
    off = (off + bytes + 255) & ~(size_t)255;
    return p;
  };
  // persistent / small
  bf16*  Wsk0t  = (bf16*)alloc((size_t)HID * K0 * 2);
  bf16*  Wsk1t  = (bf16*)alloc((size_t)HID * HID * 2);
  bf16*  Wm1t   = (bf16*)alloc((size_t)HID * HID * 2);
  bf16*  Wm2t   = (bf16*)alloc((size_t)OUTP * HID * 2);
  bf16*  W0t    = (bf16*)alloc((size_t)NREL * HID * K0 * 2);
  bf16*  W1t    = (bf16*)alloc((size_t)NREL * HID * HID * 2);
  bf16*  Brec0  = (bf16*)alloc((size_t)4 * 128 * NREL * K0 * 2);
  bf16*  Brec1  = (bf16*)alloc((size_t)4 * 128 * NREL * HID * 2);
  bf16*  wvec0  = (bf16*)alloc((size_t)128 * K0 * 2);
  bf16*  wvec1  = (bf16*)alloc((size_t)128 * HID * 2);
  float* biasb  = (float*)alloc(HID * 4);
  float* statsb = (float*)alloc(1024 * 4);
  int*   offb   = (int*)alloc((size_t)(NREL * N1 + 1) * 4);
  int*   curb   = (int*)alloc((size_t)NREL * N1 * 4);
  int*   bsumsb = (int*)alloc(1024 * 4);
  int*   srtb   = (int*)alloc((size_t)E0 * 4);
  float* out0   = (float*)alloc((size_t)N1P * HID * 4);
  bf16*  h1b    = (bf16*)alloc((size_t)N1P * HID * 2);
  bf16*  h2b    = (bf16*)alloc((size_t)N2P * HID * 2);
  bf16*  zbb    = (bf16*)alloc((size_t)N2P * HID * 2);
  float* out1   = (float*)alloc((size_t)N2P * HID * 4);
  float* zf     = (float*)alloc((size_t)N2P * HID * 4);
  // big regions
  bf16*  xb        = (bf16*)alloc((size_t)M0P * K0 * 2);
  float* scoresbuf = (float*)alloc((size_t)M0P * 128 * 4);
  bf16*  aggx      = (bf16*)alloc((size_t)4 * N1P * NREL * K0 * 2);  // reused for layer 1

  auto build_csr = [&](const int* es, const int* ed, const int* et, int E, int ndst) {
    int nkeys = NREL * ndst;
    int nbE = (E + 255) / 256;
    int nbK = (nkeys + 255) / 256;
    fill_i32_k<<<nbK, 256, 0, stream>>>(curb, 0, nkeys);
    hist_k<<<nbE, 256, 0, stream>>>(et, ed, curb, E, ndst);
    scan1_k<<<nbK, 256, 0, stream>>>(curb, offb, bsumsb, nkeys);
    scan2_k<<<1, 1024, 0, stream>>>(bsumsb, nbK);
    add_off_k<<<nbK, 256, 0, stream>>>(offb, bsumsb, nkeys);
    copy_cursor_k<<<nbK, 256, 0, stream>>>(offb, curb, nkeys, E);
    scatter_k<<<nbE, 256, 0, stream>>>(es, ed, et, curb, srtb, E, ndst);
  };

  // ---- weight prep ----
  cast_pad_k<<<((size_t)M0P * K0 / 8 + 255) / 256, 256, 0, stream>>>(
      x, xb, (long)M0 * K0, (long)M0P * K0);
  for (int j = 0; j < NREL; j++)
    transpose_cast_k<<<dim3(3, 512), 256, 0, stream>>>(
        W0 + (size_t)j * K0 * HID, W0t + (size_t)j * HID * K0, K0, HID, HID);
  transpose_cast_k<<<dim3(3, 512), 256, 0, stream>>>(Wsk0, Wsk0t, K0, HID, HID);
  for (int j = 0; j < NREL; j++)
    transpose_cast_k<<<dim3(2, 512), 256, 0, stream>>>(
        W1 + (size_t)j * HID * HID, W1t + (size_t)j * HID * HID, HID, HID, HID);
  transpose_cast_k<<<dim3(2, 512), 256, 0, stream>>>(Wsk1, Wsk1t, HID, HID, HID);
  transpose_cast_k<<<dim3(2, 512), 256, 0, stream>>>(Wm1, Wm1t, HID, HID, HID);
  transpose_cast_k<<<dim3(2, OUTP), 256, 0, stream>>>(Wm2, Wm2t, HID, OUTC, OUTC);
  reorder_brec_k<<<(4 * 128 * NREL * K0) / 256, 256, 0, stream>>>(W0t, Brec0, K0);
  reorder_brec_k<<<(4 * 128 * NREL * HID) / 256, 256, 0, stream>>>(W1t, Brec1, HID);
  wvec_k<<<dim3(K0 / 64, 128), 64, 0, stream>>>(W0, as0, ad0, wvec0, K0);
  wvec_k<<<dim3(HID / 64, 128), 64, 0, stream>>>(W1, as1, ad1, wvec1, HID);

  // ---- layer 0 ----
  {
    const int KT = NREL * K0;  // 3840
    build_csr(es0, ed0, et0, E0, N1);
    gemm_bt<1><<<dim3(M0P / 128, 1), 256, 0, stream>>>(xb, wvec0, scoresbuf, 128, K0, 0, 0, 0, nullptr);
    gemm_bt<1><<<dim3(N1P / 128, 4), 256, 0, stream>>>(xb, Wsk0t, out0, HID, K0, 0, 0, 0, nullptr);
    // zero pad rows of aggx (d in [N1, N1P))
    for (int h = 0; h < 4; h++)
      fill_i32_k<<<((N1P - N1) * KT * 2 / 4 + 255) / 256, 256, 0, stream>>>(
          (int*)(aggx + ((size_t)h * N1P + N1) * KT), 0, (N1P - N1) * KT / 2);
    agg_x_k<K0, K0 / 256><<<dim3(N1 / 8, NREL), 256, 0, stream>>>(
        srtb, offb, scoresbuf, xb, aggx, N1, N1P);
    gemm_recomb<<<dim3(N1P / 128, 1, 4), 256, 0, stream>>>(
        aggx, (size_t)N1P * KT, Brec0, (size_t)128 * KT, out0, KT);
    bias_combine_k<<<2, 256, 0, stream>>>(bsk0, b0, biasb, NREL);
    fill_f32_k<<<4, 256, 0, stream>>>(statsb, 0.f, 1024);
    bn_stats_k<<<256, 256, 0, stream>>>(out0, biasb, statsb, statsb + 512, N1);
    bn_apply_k<0><<<(N1P * HID) / 256, 256, 0, stream>>>(out0, biasb, statsb, statsb + 512,
                                                         g0, be0, h1b, N1, 1.f / N1);
  }

  // ---- layer 1 ----
  {
    const int KT = NREL * HID;  // 2560
    build_csr(es1, ed1, et1, E1, N2);
    gemm_bt<1><<<dim3(N1P / 128, 1), 256, 0, stream>>>(h1b, wvec1, scoresbuf, 128, HID, 0, 0, 0, nullptr);
    gemm_bt<1><<<dim3(N2P / 128, 4), 256, 0, stream>>>(h1b, Wsk1t, out1, HID, HID, 0, 0, 0, nullptr);
    for (int h = 0; h < 4; h++)
      fill_i32_k<<<((N2P - N2) * KT * 2 / 4 + 255) / 256, 256, 0, stream>>>(
          (int*)(aggx + ((size_t)h * N2P + N2) * KT), 0, (N2P - N2) * KT / 2);
    agg_x_k<HID, HID / 256><<<dim3(N2 / 8, NREL), 256, 0, stream>>>(
        srtb, offb, scoresbuf, h1b, aggx, N2, N2P);
    gemm_recomb<<<dim3(N2P / 128, 1, 4), 256, 0, stream>>>(
        aggx, (size_t)N2P * KT, Brec1, (size_t)128 * KT, out1, KT);
    bias_combine_k<<<2, 256, 0, stream>>>(bsk1, b1, biasb, NREL);
    fill_f32_k<<<4, 256, 0, stream>>>(statsb, 0.f, 1024);
    bn_stats_k<<<256, 256, 0, stream>>>(out1, biasb, statsb, statsb + 512, N2);
    bn_apply_k<0><<<(N2P * HID) / 256, 256, 0, stream>>>(out1, biasb, statsb, statsb + 512,
                                                         g1, be1, h2b, N2, 1.f / N2);
  }

  // ---- MLP head ----
  gemm_bt<1><<<dim3(N2P / 128, 4), 256, 0, stream>>>(h2b, Wm1t, zf, HID, HID, 0, 0, 0, nullptr);
  fill_f32_k<<<4, 256, 0, stream>>>(statsb, 0.f, 1024);
  bn_stats_k<<<256, 256, 0, stream>>>(zf, bm1, statsb, statsb + 512, N2);
  bn_apply_k<1><<<(N2P * HID) / 256, 256, 0, stream>>>(zf, bm1, statsb, statsb + 512,
                                                       gm, bmn, zbb, N2, 1.f / N2);
  gemm_bt<2><<<dim3(N2P / 128, OUTP / 128), 256, 0, stream>>>(
      zbb, Wm2t, d_out, OUTP, HID, N2, OUTC, OUTC, bm2);

  (void)in_sizes; (void)n_in; (void)out_size; (void)ws_size;
}

// Round 6
// 2000.879 us; speedup vs baseline: 1.0074x; 1.0064x over previous
//
#include <hip/hip_runtime.h>
#include <math.h>

typedef __bf16 bf16;
typedef __bf16 bf16x4 __attribute__((ext_vector_type(4)));
typedef __bf16 bf16x8 __attribute__((ext_vector_type(8)));
typedef float f32x4 __attribute__((ext_vector_type(4)));

#define M0   120000
#define M0P  120064   // 938*128
#define K0   768
#define HID  512
#define NREL 5
#define N1   30000
#define N1P  30080    // 235*128
#define E0   600000
#define N2   8000
#define N2P  8064     // 63*128
#define E1   150000
#define OUTC 153
#define OUTP 256

#define GLOAD_LDS16(g, s) \
  __builtin_amdgcn_global_load_lds((const __attribute__((address_space(1))) void*)(g), \
                                   (__attribute__((address_space(3))) void*)(s), 16, 0, 0)

// ---------------------------------------------------------------------------
// GEMM: C[M x N] = A[M x K](bf16 rm) * Bt[N x K](bf16 rm)^T
// MODE 1: store f32, ldc=N. MODE 2: f32+bias, guarded, ldc param.
// ---------------------------------------------------------------------------
template <int MODE>
__global__ __launch_bounds__(256) void gemm_bt(
    const bf16* __restrict__ A, const bf16* __restrict__ Bt, void* __restrict__ Cout,
    int N, int K, int Mv, int Nv, int ldc, const float* __restrict__ bias)
{
  __shared__ __attribute__((aligned(16))) bf16 As[128 * 32];
  __shared__ __attribute__((aligned(16))) bf16 Bs[128 * 32];
  const int tid = threadIdx.x;
  const int w = tid >> 6, l = tid & 63;
  const int tm = blockIdx.x * 128, tn = blockIdx.y * 128;
  const int wm = (w >> 1) * 64, wn = (w & 1) * 64;
  const int lr = l & 15, q = l >> 4;

  f32x4 acc[4][4] = {};

  const int arow = l >> 2;
  const int acol = (l & 3) * 8;
  const bf16* Ag = A + (size_t)tm * K + acol;
  const bf16* Bg = Bt + (size_t)tn * K + acol;

  for (int k0 = 0; k0 < K; k0 += 32) {
#pragma unroll
    for (int i = 0; i < 2; i++) {
      int rb = __builtin_amdgcn_readfirstlane(16 * (2 * w + i));
      GLOAD_LDS16(Ag + (size_t)(rb + arow) * K + k0, As + rb * 32);
      GLOAD_LDS16(Bg + (size_t)(rb + arow) * K + k0, Bs + rb * 32);
    }
    __syncthreads();
    bf16x8 af[4], bfr[4];
#pragma unroll
    for (int i = 0; i < 4; i++)
      af[i] = *(const bf16x8*)&As[(wm + i * 16 + lr) * 32 + q * 8];
#pragma unroll
    for (int jj = 0; jj < 4; jj++)
      bfr[jj] = *(const bf16x8*)&Bs[(wn + jj * 16 + lr) * 32 + q * 8];
#pragma unroll
    for (int i = 0; i < 4; i++)
#pragma unroll
      for (int jj = 0; jj < 4; jj++)
        acc[i][jj] = __builtin_amdgcn_mfma_f32_16x16x32_bf16(af[i], bfr[jj], acc[i][jj], 0, 0, 0);
    __syncthreads();
  }

#pragma unroll
  for (int i = 0; i < 4; i++)
#pragma unroll
    for (int jj = 0; jj < 4; jj++)
#pragma unroll
      for (int r = 0; r < 4; r++) {
        int row = tm + wm + i * 16 + q * 4 + r;
        int col = tn + wn + jj * 16 + lr;
        float v = acc[i][jj][r];
        if (MODE == 1) {
          ((float*)Cout)[(size_t)row * N + col] = v;
        } else {
          if (row < Mv && col < Nv)
            ((float*)Cout)[(size_t)row * ldc + col] = v + bias[col];
        }
      }
}

// ---------------------------------------------------------------------------
// fused head-recombination + skip GEMM:
// C[tm.., z*128+c] = A_z[tm..,:Kagg] @ B_z[c,:Kagg]^T + Xs[tm..,:Ks] @ Wskt[z*128+c,:Ks]^T
// A_z = A0 + z*sA (bf16 rm, ld=Kagg); B_z = B0 + z*sB (128 x Kagg bf16 rm);
// Xs (bf16 rm, ld=Ks); Wskt (512 x Ks bf16 rm). C f32, ldc=512, plain store
// (removes the separate skip GEMM launch and the C read-modify-write).
// ---------------------------------------------------------------------------
__global__ __launch_bounds__(256) void gemm_recomb_fused(
    const bf16* __restrict__ A0, size_t sA, const bf16* __restrict__ B0, size_t sB,
    const bf16* __restrict__ Xs, const bf16* __restrict__ Wskt,
    float* __restrict__ C, int Kagg, int Ks)
{
  __shared__ __attribute__((aligned(16))) bf16 As[128 * 32];
  __shared__ __attribute__((aligned(16))) bf16 Bs[128 * 32];
  const int z = blockIdx.y;
  const bf16* A = A0 + (size_t)z * sA;
  const bf16* Bt = B0 + (size_t)z * sB;
  const int tid = threadIdx.x;
  const int w = tid >> 6, l = tid & 63;
  const int tm = blockIdx.x * 128;
  const int wm = (w >> 1) * 64, wn = (w & 1) * 64;
  const int lr = l & 15, q = l >> 4;

  f32x4 acc[4][4] = {};
  const int arow = l >> 2;
  const int acol = (l & 3) * 8;

#define RECOMB_KSTEP(AgP, BgP, LDK)                                            \
  {                                                                            \
    _Pragma("unroll")                                                          \
    for (int i = 0; i < 2; i++) {                                              \
      int rb = __builtin_amdgcn_readfirstlane(16 * (2 * w + i));               \
      GLOAD_LDS16((AgP) + (size_t)(rb + arow) * (LDK) + k0, As + rb * 32);     \
      GLOAD_LDS16((BgP) + (size_t)(rb + arow) * (LDK) + k0, Bs + rb * 32);     \
    }                                                                          \
    __syncthreads();                                                           \
    bf16x8 af[4], bfr[4];                                                      \
    _Pragma("unroll")                                                          \
    for (int i = 0; i < 4; i++)                                                \
      af[i] = *(const bf16x8*)&As[(wm + i * 16 + lr) * 32 + q * 8];            \
    _Pragma("unroll")                                                          \
    for (int jj = 0; jj < 4; jj++)                                             \
      bfr[jj] = *(const bf16x8*)&Bs[(wn + jj * 16 + lr) * 32 + q * 8];         \
    _Pragma("unroll")                                                          \
    for (int i = 0; i < 4; i++)                                                \
      _Pragma("unroll")                                                        \
      for (int jj = 0; jj < 4; jj++)                                           \
        acc[i][jj] = __builtin_amdgcn_mfma_f32_16x16x32_bf16(af[i], bfr[jj],   \
                                                             acc[i][jj], 0, 0, 0); \
    __syncthreads();                                                           \
  }

  {
    const bf16* Ag = A + (size_t)tm * Kagg + acol;
    const bf16* Bg = Bt + acol;
    for (int k0 = 0; k0 < Kagg; k0 += 32) RECOMB_KSTEP(Ag, Bg, Kagg)
  }
  {
    const bf16* Ag = Xs + (size_t)tm * Ks + acol;
    const bf16* Bg = Wskt + (size_t)(z * 128) * Ks + acol;
    for (int k0 = 0; k0 < Ks; k0 += 32) RECOMB_KSTEP(Ag, Bg, Ks)
  }
#undef RECOMB_KSTEP

#pragma unroll
  for (int i = 0; i < 4; i++)
#pragma unroll
    for (int jj = 0; jj < 4; jj++)
#pragma unroll
      for (int r = 0; r < 4; r++) {
        int row = tm + wm + i * 16 + q * 4 + r;
        int col = z * 128 + wn + jj * 16 + lr;
        C[(size_t)row * 512 + col] = acc[i][jj][r];
      }
}

// ---------------------------------------------------------------------------
__global__ void cast_pad_k(const float* __restrict__ src, bf16* __restrict__ dst,
                           long nvalid, long ntot)
{
  long i = ((long)blockIdx.x * 256 + threadIdx.x) * 8;
  if (i >= ntot) return;
  bf16x8 o;
  if (i + 8 <= nvalid) {
    float4 v0 = *(const float4*)(src + i);
    float4 v1 = *(const float4*)(src + i + 4);
    o[0] = (bf16)v0.x; o[1] = (bf16)v0.y; o[2] = (bf16)v0.z; o[3] = (bf16)v0.w;
    o[4] = (bf16)v1.x; o[5] = (bf16)v1.y; o[6] = (bf16)v1.z; o[7] = (bf16)v1.w;
  } else {
#pragma unroll
    for (int t = 0; t < 8; t++)
      o[t] = (i + t < nvalid) ? (bf16)src[i + t] : (bf16)0.f;
  }
  *(bf16x8*)(dst + i) = o;
}

__global__ void transpose_cast_k(const float* __restrict__ W, bf16* __restrict__ Wt,
                                 int K, int Nsrc, int Nvalid)
{
  int n = blockIdx.y;
  int k = blockIdx.x * 256 + threadIdx.x;
  Wt[(size_t)n * K + k] = (n < Nvalid) ? (bf16)W[(size_t)k * Nsrc + n] : (bf16)0.f;
}

// Brec[h][c][j*K+k] = Wt[j*512 + h*128 + c][k]; flat i = ((h*128+c)*NREL + j)*K + k
__global__ void reorder_brec_k(const bf16* __restrict__ Wt, bf16* __restrict__ Brec, int K)
{
  int i = blockIdx.x * 256 + threadIdx.x;
  int k = i % K;
  int rest = i / K;
  int j = rest % NREL;
  int rest2 = rest / NREL;
  int c = rest2 & 127;
  int h = rest2 >> 7;
  Brec[i] = Wt[((size_t)(j * 512 + h * 128 + c)) * K + k];
}

// wvec[col][k] = sum_c W[j][k][h*128+c] * a[j][h][c]; col = j*8 + side*4 + h (<40)
__global__ void wvec_k(const float* __restrict__ W, const float* __restrict__ a_s,
                       const float* __restrict__ a_d, bf16* __restrict__ wv, int K)
{
  int k = blockIdx.x * 64 + threadIdx.x;
  int col = blockIdx.y;
  float v = 0.f;
  if (col < 40) {
    int j = col >> 3, side = (col >> 2) & 1, h = col & 3;
    const float* Wrow = W + ((size_t)j * K + k) * 512 + h * 128;
    const float* av = (side ? a_d : a_s) + (j * 4 + h) * 128;
    for (int c = 0; c < 128; c++) v += Wrow[c] * av[c];
  }
  wv[(size_t)col * K + k] = (bf16)v;
}

// ---------------------------------------------------------------------------
// CSR build
// ---------------------------------------------------------------------------
__global__ void fill_i32_k(int* __restrict__ p, int v, int n)
{
  int i = blockIdx.x * 256 + threadIdx.x;
  if (i < n) p[i] = v;
}

__global__ void hist_k(const int* __restrict__ et, const int* __restrict__ ed,
                       int* __restrict__ cnt, int E, int ndst)
{
  int e = blockIdx.x * 256 + threadIdx.x;
  if (e >= E) return;
  atomicAdd(&cnt[et[e] * ndst + ed[e]], 1);
}

__global__ void scan1_k(const int* __restrict__ in, int* __restrict__ out,
                        int* __restrict__ bsums, int n)
{
  __shared__ int sh[256];
  int t = threadIdx.x;
  int i = blockIdx.x * 256 + t;
  int v = (i < n) ? in[i] : 0;
  sh[t] = v;
  __syncthreads();
#pragma unroll
  for (int o = 1; o < 256; o <<= 1) {
    int x = 0;
    if (t >= o) x = sh[t - o];
    __syncthreads();
    if (t >= o) sh[t] += x;
    __syncthreads();
  }
  if (i < n) out[i] = sh[t] - v;
  if (t == 255) bsums[blockIdx.x] = sh[255];
}

__global__ void scan2_k(int* __restrict__ b, int n)
{
  __shared__ int sh[1024];
  int t = threadIdx.x;
  int v = (t < n) ? b[t] : 0;
  sh[t] = v;
  __syncthreads();
#pragma unroll
  for (int o = 1; o < 1024; o <<= 1) {
    int x = 0;
    if (t >= o) x = sh[t - o];
    __syncthreads();
    if (t >= o) sh[t] += x;
    __syncthreads();
  }
  if (t < n) b[t] = sh[t] - v;
}

__global__ void add_off_k(int* __restrict__ out, const int* __restrict__ bscan, int n)
{
  int i = blockIdx.x * 256 + threadIdx.x;
  if (i < n) out[i] += bscan[blockIdx.x];
}

__global__ void copy_cursor_k(int* __restrict__ off, int* __restrict__ cur, int n, int E)
{
  int i = blockIdx.x * 256 + threadIdx.x;
  if (i < n) cur[i] = off[i];
  if (i == 0) off[n] = E;
}

__global__ void scatter_k(const int* __restrict__ es, const int* __restrict__ ed,
                          const int* __restrict__ et, int* __restrict__ cur,
                          int* __restrict__ sorted_src, int E, int ndst)
{
  int e = blockIdx.x * 256 + threadIdx.x;
  if (e >= E) return;
  int pos = atomicAdd(&cur[et[e] * ndst + ed[e]], 1);
  sorted_src[pos] = es[e];
}

// ---------------------------------------------------------------------------
// x-space softmax-aggregate, HEAD-PAIR SPLIT version (r2 loop structure).
// grid = (ndst/2, NREL) x 256 threads: each block = 2 dst keys x 2 head-pair
// waves. Each wave runs the proven r2 loop (depth-1 prefetch, no explicit
// waits, no LDS) but for only 2 of the 4 heads -> 2x independent gather
// chains per CU at LOWER VGPR than r2 (half the accumulators). The sibling
// wave's duplicate X-row read is same-CU-co-resident -> L2 hit.
// Single-pass softmax (scores are O(0.3): exp(s)/sum exp(s) == softmax).
// aggx[h][d][j*K + k] = sum_e alpha[e,h] * X[src_e][k]  (bf16 out, f32 acc)
// scoresbuf [.][128]: col j*8+h = a_s, col j*8+4+h = a_d
// ---------------------------------------------------------------------------
template <int K, int CH>   // CH = K/256  (bf16x4 chunks per lane)
__global__ __launch_bounds__(256) void agg_x_k(
    const int* __restrict__ sorted_src, const int* __restrict__ off,
    const float* __restrict__ scoresbuf, const bf16* __restrict__ X,
    bf16* __restrict__ aggx, int ndst, int nrows)
{
  const int wv = threadIdx.x >> 6;
  const int l  = threadIdx.x & 63;
  const int d  = blockIdx.x * 2 + (wv >> 1);
  const int hp = wv & 1;               // heads {2*hp, 2*hp+1}
  const int j  = blockIdx.y;
  if (d >= ndst) return;
  const int key = j * ndst + d;
  const int beg = off[key], end = off[key + 1];
  const float2 svd = *(const float2*)(scoresbuf + (size_t)d * 128 + j * 8 + 4 + hp * 2);
  const int lane_off = l * (CH * 4);

  float den0 = 0.f, den1 = 0.f;
  f32x4 acc0[CH] = {}, acc1[CH] = {};

  int p = beg;
  float2 sv0;
  bf16x4 xv0[CH];
  if (p < end) {
    int s0 = sorted_src[p];
    sv0 = *(const float2*)(scoresbuf + (size_t)s0 * 128 + j * 8 + hp * 2);
    const bf16* xr = X + (size_t)s0 * K + lane_off;
#pragma unroll
    for (int c = 0; c < CH; c++) xv0[c] = *(const bf16x4*)(xr + c * 4);
  }
  while (p < end) {
    const bool more = (p + 1 < end);
    float2 sv1;
    bf16x4 xv1[CH];
    if (more) {
      int s1 = sorted_src[p + 1];
      sv1 = *(const float2*)(scoresbuf + (size_t)s1 * 128 + j * 8 + hp * 2);
      const bf16* xr = X + (size_t)s1 * K + lane_off;
#pragma unroll
      for (int c = 0; c < CH; c++) xv1[c] = *(const bf16x4*)(xr + c * 4);
    }
    float v0 = sv0.x + svd.x, v1 = sv0.y + svd.y;
    float t0 = v0 > 0.f ? v0 : 0.2f * v0;
    float t1 = v1 > 0.f ? v1 : 0.2f * v1;
    float e0 = __expf(t0), e1 = __expf(t1);
    den0 += e0; den1 += e1;
    f32x4 xf[CH];
#pragma unroll
    for (int c = 0; c < CH; c++) {
#pragma unroll
      for (int t = 0; t < 4; t++) xf[c][t] = (float)xv0[c][t];
    }
#pragma unroll
    for (int c = 0; c < CH; c++) {
      acc0[c] += e0 * xf[c];
      acc1[c] += e1 * xf[c];
    }
    p++;
    if (more) {
      sv0 = sv1;
#pragma unroll
      for (int c = 0; c < CH; c++) xv0[c] = xv1[c];
    }
  }

  {
    float sc0 = 1.f / fmaxf(den0, 1e-16f);
    float sc1 = 1.f / fmaxf(den1, 1e-16f);
    const int h0 = hp * 2;
    bf16* orow0 = aggx + ((size_t)h0 * nrows + d) * ((size_t)NREL * K) + (size_t)j * K + lane_off;
    bf16* orow1 = aggx + ((size_t)(h0 + 1) * nrows + d) * ((size_t)NREL * K) + (size_t)j * K + lane_off;
#pragma unroll
    for (int c = 0; c < CH; c++) {
      bf16x4 o0, o1;
#pragma unroll
      for (int t = 0; t < 4; t++) {
        o0[t] = (bf16)(acc0[c][t] * sc0);
        o1[t] = (bf16)(acc1[c][t] * sc1);
      }
      *(bf16x4*)(orow0 + c * 4) = o0;
      *(bf16x4*)(orow1 + c * 4) = o1;
    }
  }
}

// ---------------------------------------------------------------------------
__global__ void bias_combine_k(const float* __restrict__ bsk, const float* __restrict__ brel,
                               float* __restrict__ out, int R)
{
  int c = blockIdx.x * 256 + threadIdx.x;
  if (c >= HID) return;
  float v = bsk[c];
  for (int j = 0; j < R; j++) v += brel[j * HID + c];
  out[c] = v;
}

__global__ void fill_f32_k(float* __restrict__ p, float v, int n)
{
  int i = blockIdx.x * 256 + threadIdx.x;
  if (i < n) p[i] = v;
}

__global__ void bn_stats_k(const float* __restrict__ X, const float* __restrict__ bias,
                           float* __restrict__ sums, float* __restrict__ sumsq, int rows)
{
  int t = threadIdx.x;
  int c0 = t * 2;
  float b0 = bias[c0], b1 = bias[c0 + 1];
  float s0 = 0, s1 = 0, q0 = 0, q1 = 0;
  for (int r = blockIdx.x; r < rows; r += gridDim.x) {
    float2 v = *(const float2*)(X + (size_t)r * HID + c0);
    float v0 = v.x + b0, v1 = v.y + b1;
    s0 += v0; q0 += v0 * v0;
    s1 += v1; q1 += v1 * v1;
  }
  atomicAdd(sums + c0, s0); atomicAdd(sums + c0 + 1, s1);
  atomicAdd(sumsq + c0, q0); atomicAdd(sumsq + c0 + 1, q1);
}

template <int ACT>
__global__ void bn_apply_k(const float* __restrict__ X, const float* __restrict__ bias,
                           const float* __restrict__ sums, const float* __restrict__ sumsq,
                           const float* __restrict__ gamma, const float* __restrict__ beta,
                           bf16* __restrict__ Y, int rows, float invN)
{
  int idx = blockIdx.x * 256 + threadIdx.x;
  int row = idx >> 9, c = idx & 511;
  float y = 0.f;
  if (row < rows) {
    float mu = sums[c] * invN;
    float var = sumsq[c] * invN - mu * mu;
    float v = X[idx] + bias[c];
    float xn = (v - mu) * rsqrtf(var + 1e-5f);
    y = gamma[c] * xn + beta[c];
    y = (ACT == 0) ? (y > 0.f ? y : expm1f(y)) : fmaxf(y, 0.f);
  }
  Y[idx] = (bf16)y;
}

// ---------------------------------------------------------------------------
extern "C" void kernel_launch(void* const* d_in, const int* in_sizes, int n_in,
                              void* d_out, int out_size, void* d_ws, size_t ws_size,
                              hipStream_t stream)
{
  const float* x    = (const float*)d_in[0];
  const int*   es0  = (const int*)d_in[1];
  const int*   ed0  = (const int*)d_in[2];
  const int*   et0  = (const int*)d_in[3];
  const int*   es1  = (const int*)d_in[4];
  const int*   ed1  = (const int*)d_in[5];
  const int*   et1  = (const int*)d_in[6];
  const float* W0   = (const float*)d_in[7];
  const float* as0  = (const float*)d_in[8];
  const float* ad0  = (const float*)d_in[9];
  const float* b0   = (const float*)d_in[10];
  const float* Wsk0 = (const float*)d_in[11];
  const float* bsk0 = (const float*)d_in[12];
  const float* g0   = (const float*)d_in[13];
  const float* be0  = (const float*)d_in[14];
  const float* W1   = (const float*)d_in[15];
  const float* as1  = (const float*)d_in[16];
  const float* ad1  = (const float*)d_in[17];
  const float* b1   = (const float*)d_in[18];
  const float* Wsk1 = (const float*)d_in[19];
  const float* bsk1 = (const float*)d_in[20];
  const float* g1   = (const float*)d_in[21];
  const float* be1  = (const float*)d_in[22];
  const float* Wm1  = (const float*)d_in[23];
  const float* bm1  = (const float*)d_in[24];
  const float* gm   = (const float*)d_in[25];
  const float* bmn  = (const float*)d_in[26];
  const float* Wm2  = (const float*)d_in[27];
  const float* bm2  = (const float*)d_in[28];

  char* wsb = (char*)d_ws;
  size_t off = 0;
  auto alloc = [&](size_t bytes) -> char* {
    char* p = wsb + off;
    off = (off + bytes + 255) & ~(size_t)255;
    return p;
  };
  // persistent / small
  bf16*  Wsk0t  = (bf16*)alloc((size_t)HID * K0 * 2);
  bf16*  Wsk1t  = (bf16*)alloc((size_t)HID * HID * 2);
  bf16*  Wm1t   = (bf16*)alloc((size_t)HID * HID * 2);
  bf16*  Wm2t   = (bf16*)alloc((size_t)OUTP * HID * 2);
  bf16*  W0t    = (bf16*)alloc((size_t)NREL * HID * K0 * 2);
  bf16*  W1t    = (bf16*)alloc((size_t)NREL * HID * HID * 2);
  bf16*  Brec0  = (bf16*)alloc((size_t)4 * 128 * NREL * K0 * 2);
  bf16*  Brec1  = (bf16*)alloc((size_t)4 * 128 * NREL * HID * 2);
  bf16*  wvec0  = (bf16*)alloc((size_t)128 * K0 * 2);
  bf16*  wvec1  = (bf16*)alloc((size_t)128 * HID * 2);
  float* biasb  = (float*)alloc(HID * 4);
  float* statsb = (float*)alloc(1024 * 4);
  int*   offb   = (int*)alloc((size_t)(NREL * N1 + 1) * 4);
  int*   curb   = (int*)alloc((size_t)NREL * N1 * 4);
  int*   bsumsb = (int*)alloc(1024 * 4);
  int*   srtb   = (int*)alloc((size_t)E0 * 4);
  float* out0   = (float*)alloc((size_t)N1P * HID * 4);
  bf16*  h1b    = (bf16*)alloc((size_t)N1P * HID * 2);
  bf16*  h2b    = (bf16*)alloc((size_t)N2P * HID * 2);
  bf16*  zbb    = (bf16*)alloc((size_t)N2P * HID * 2);
  float* out1   = (float*)alloc((size_t)N2P * HID * 4);
  float* zf     = (float*)alloc((size_t)N2P * HID * 4);
  // big regions
  bf16*  xb        = (bf16*)alloc((size_t)M0P * K0 * 2);
  float* scoresbuf = (float*)alloc((size_t)M0P * 128 * 4);
  bf16*  aggx      = (bf16*)alloc((size_t)4 * N1P * NREL * K0 * 2);  // reused for layer 1

  auto build_csr = [&](const int* es, const int* ed, const int* et, int E, int ndst) {
    int nkeys = NREL * ndst;
    int nbE = (E + 255) / 256;
    int nbK = (nkeys + 255) / 256;
    fill_i32_k<<<nbK, 256, 0, stream>>>(curb, 0, nkeys);
    hist_k<<<nbE, 256, 0, stream>>>(et, ed, curb, E, ndst);
    scan1_k<<<nbK, 256, 0, stream>>>(curb, offb, bsumsb, nkeys);
    scan2_k<<<1, 1024, 0, stream>>>(bsumsb, nbK);
    add_off_k<<<nbK, 256, 0, stream>>>(offb, bsumsb, nkeys);
    copy_cursor_k<<<nbK, 256, 0, stream>>>(offb, curb, nkeys, E);
    scatter_k<<<nbE, 256, 0, stream>>>(es, ed, et, curb, srtb, E, ndst);
  };

  // ---- weight prep ----
  cast_pad_k<<<((size_t)M0P * K0 / 8 + 255) / 256, 256, 0, stream>>>(
      x, xb, (long)M0 * K0, (long)M0P * K0);
  for (int j = 0; j < NREL; j++)
    transpose_cast_k<<<dim3(3, 512), 256, 0, stream>>>(
        W0 + (size_t)j * K0 * HID, W0t + (size_t)j * HID * K0, K0, HID, HID);
  transpose_cast_k<<<dim3(3, 512), 256, 0, stream>>>(Wsk0, Wsk0t, K0, HID, HID);
  for (int j = 0; j < NREL; j++)
    transpose_cast_k<<<dim3(2, 512), 256, 0, stream>>>(
        W1 + (size_t)j * HID * HID, W1t + (size_t)j * HID * HID, HID, HID, HID);
  transpose_cast_k<<<dim3(2, 512), 256, 0, stream>>>(Wsk1, Wsk1t, HID, HID, HID);
  transpose_cast_k<<<dim3(2, 512), 256, 0, stream>>>(Wm1, Wm1t, HID, HID, HID);
  transpose_cast_k<<<dim3(2, OUTP), 256, 0, stream>>>(Wm2, Wm2t, HID, OUTC, OUTC);
  reorder_brec_k<<<(4 * 128 * NREL * K0) / 256, 256, 0, stream>>>(W0t, Brec0, K0);
  reorder_brec_k<<<(4 * 128 * NREL * HID) / 256, 256, 0, stream>>>(W1t, Brec1, HID);
  wvec_k<<<dim3(K0 / 64, 128), 64, 0, stream>>>(W0, as0, ad0, wvec0, K0);
  wvec_k<<<dim3(HID / 64, 128), 64, 0, stream>>>(W1, as1, ad1, wvec1, HID);

  // ---- layer 0 ----
  {
    const int KT = NREL * K0;  // 3840
    build_csr(es0, ed0, et0, E0, N1);
    gemm_bt<1><<<dim3(M0P / 128, 1), 256, 0, stream>>>(xb, wvec0, scoresbuf, 128, K0, 0, 0, 0, nullptr);
    // zero pad rows of aggx (d in [N1, N1P))
    for (int h = 0; h < 4; h++)
      fill_i32_k<<<((N1P - N1) * KT * 2 / 4 + 255) / 256, 256, 0, stream>>>(
          (int*)(aggx + ((size_t)h * N1P + N1) * KT), 0, (N1P - N1) * KT / 2);
    agg_x_k<K0, K0 / 256><<<dim3(N1 / 2, NREL), 256, 0, stream>>>(
        srtb, offb, scoresbuf, xb, aggx, N1, N1P);
    gemm_recomb_fused<<<dim3(N1P / 128, 4), 256, 0, stream>>>(
        aggx, (size_t)N1P * KT, Brec0, (size_t)128 * KT, xb, Wsk0t, out0, KT, K0);
    bias_combine_k<<<2, 256, 0, stream>>>(bsk0, b0, biasb, NREL);
    fill_f32_k<<<4, 256, 0, stream>>>(statsb, 0.f, 1024);
    bn_stats_k<<<256, 256, 0, stream>>>(out0, biasb, statsb, statsb + 512, N1);
    bn_apply_k<0><<<(N1P * HID) / 256, 256, 0, stream>>>(out0, biasb, statsb, statsb + 512,
                                                         g0, be0, h1b, N1, 1.f / N1);
  }

  // ---- layer 1 ----
  {
    const int KT = NREL * HID;  // 2560
    build_csr(es1, ed1, et1, E1, N2);
    gemm_bt<1><<<dim3(N1P / 128, 1), 256, 0, stream>>>(h1b, wvec1, scoresbuf, 128, HID, 0, 0, 0, nullptr);
    for (int h = 0; h < 4; h++)
      fill_i32_k<<<((N2P - N2) * KT * 2 / 4 + 255) / 256, 256, 0, stream>>>(
          (int*)(aggx + ((size_t)h * N2P + N2) * KT), 0, (N2P - N2) * KT / 2);
    agg_x_k<HID, HID / 256><<<dim3(N2 / 2, NREL), 256, 0, stream>>>(
        srtb, offb, scoresbuf, h1b, aggx, N2, N2P);
    gemm_recomb_fused<<<dim3(N2P / 128, 4), 256, 0, stream>>>(
        aggx, (size_t)N2P * KT, Brec1, (size_t)128 * KT, h1b, Wsk1t, out1, KT, HID);
    bias_combine_k<<<2, 256, 0, stream>>>(bsk1, b1, biasb, NREL);
    fill_f32_k<<<4, 256, 0, stream>>>(statsb, 0.f, 1024);
    bn_stats_k<<<256, 256, 0, stream>>>(out1, biasb, statsb, statsb + 512, N2);
    bn_apply_k<0><<<(N2P * HID) / 256, 256, 0, stream>>>(out1, biasb, statsb, statsb + 512,
                                                         g1, be1, h2b, N2, 1.f / N2);
  }

  // ---- MLP head ----
  gemm_bt<1><<<dim3(N2P / 128, 4), 256, 0, stream>>>(h2b, Wm1t, zf, HID, HID, 0, 0, 0, nullptr);
  fill_f32_k<<<4, 256, 0, stream>>>(statsb, 0.f, 1024);
  bn_stats_k<<<256, 256, 0, stream>>>(zf, bm1, statsb, statsb + 512, N2);
  bn_apply_k<1><<<(N2P * HID) / 256, 256, 0, stream>>>(zf, bm1, statsb, statsb + 512,
                                                       gm, bmn, zbb, N2, 1.f / N2);
  gemm_bt<2><<<dim3(N2P / 128, OUTP / 128), 256, 0, stream>>>(
      zbb, Wm2t, d_out, OUTP, HID, N2, OUTC, OUTC, bm2);

  (void)in_sizes; (void)n_in; (void)out_size; (void)ws_size;
}

// Round 8
// 1897.461 us; speedup vs baseline: 1.0623x; 1.0545x over previous
//
#include <hip/hip_runtime.h>
#include <math.h>

typedef __bf16 bf16;
typedef __bf16 bf16x4 __attribute__((ext_vector_type(4)));
typedef __bf16 bf16x8 __attribute__((ext_vector_type(8)));
typedef float f32x4 __attribute__((ext_vector_type(4)));

#define M0   120000
#define M0P  120064   // 938*128
#define K0   768
#define HID  512
#define NREL 5
#define N1   30000
#define N1P  30080    // 235*128
#define E0   600000
#define N2   8000
#define N2P  8064     // 63*128
#define E1   150000
#define OUTC 153
#define OUTP 256

#define GLOAD_LDS16(g, s) \
  __builtin_amdgcn_global_load_lds((const __attribute__((address_space(1))) void*)(g), \
                                   (__attribute__((address_space(3))) void*)(s), 16, 0, 0)

// ---------------------------------------------------------------------------
// GEMM: C[M x N] = A[M x K](bf16 rm) * Bt[N x K](bf16 rm)^T
// MODE 1: store f32, ldc=N. MODE 2: f32+bias, guarded, ldc param.
// ---------------------------------------------------------------------------
template <int MODE>
__global__ __launch_bounds__(256) void gemm_bt(
    const bf16* __restrict__ A, const bf16* __restrict__ Bt, void* __restrict__ Cout,
    int N, int K, int Mv, int Nv, int ldc, const float* __restrict__ bias)
{
  __shared__ __attribute__((aligned(16))) bf16 As[128 * 32];
  __shared__ __attribute__((aligned(16))) bf16 Bs[128 * 32];
  const int tid = threadIdx.x;
  const int w = tid >> 6, l = tid & 63;
  const int tm = blockIdx.x * 128, tn = blockIdx.y * 128;
  const int wm = (w >> 1) * 64, wn = (w & 1) * 64;
  const int lr = l & 15, q = l >> 4;

  f32x4 acc[4][4] = {};

  const int arow = l >> 2;
  const int acol = (l & 3) * 8;
  const bf16* Ag = A + (size_t)tm * K + acol;
  const bf16* Bg = Bt + (size_t)tn * K + acol;

  for (int k0 = 0; k0 < K; k0 += 32) {
#pragma unroll
    for (int i = 0; i < 2; i++) {
      int rb = __builtin_amdgcn_readfirstlane(16 * (2 * w + i));
      GLOAD_LDS16(Ag + (size_t)(rb + arow) * K + k0, As + rb * 32);
      GLOAD_LDS16(Bg + (size_t)(rb + arow) * K + k0, Bs + rb * 32);
    }
    __syncthreads();
    bf16x8 af[4], bfr[4];
#pragma unroll
    for (int i = 0; i < 4; i++)
      af[i] = *(const bf16x8*)&As[(wm + i * 16 + lr) * 32 + q * 8];
#pragma unroll
    for (int jj = 0; jj < 4; jj++)
      bfr[jj] = *(const bf16x8*)&Bs[(wn + jj * 16 + lr) * 32 + q * 8];
#pragma unroll
    for (int i = 0; i < 4; i++)
#pragma unroll
      for (int jj = 0; jj < 4; jj++)
        acc[i][jj] = __builtin_amdgcn_mfma_f32_16x16x32_bf16(af[i], bfr[jj], acc[i][jj], 0, 0, 0);
    __syncthreads();
  }

#pragma unroll
  for (int i = 0; i < 4; i++)
#pragma unroll
    for (int jj = 0; jj < 4; jj++)
#pragma unroll
      for (int r = 0; r < 4; r++) {
        int row = tm + wm + i * 16 + q * 4 + r;
        int col = tn + wn + jj * 16 + lr;
        float v = acc[i][jj][r];
        if (MODE == 1) {
          ((float*)Cout)[(size_t)row * N + col] = v;
        } else {
          if (row < Mv && col < Nv)
            ((float*)Cout)[(size_t)row * ldc + col] = v + bias[col];
        }
      }
}

// ---------------------------------------------------------------------------
// fused head-recombination + skip GEMM:
// C[tm.., z*128+c] = A_z[tm..,:Kagg] @ B_z[c,:Kagg]^T + Xs[tm..,:Ks] @ Wskt[z*128+c,:Ks]^T
// ---------------------------------------------------------------------------
__global__ __launch_bounds__(256) void gemm_recomb_fused(
    const bf16* __restrict__ A0, size_t sA, const bf16* __restrict__ B0, size_t sB,
    const bf16* __restrict__ Xs, const bf16* __restrict__ Wskt,
    float* __restrict__ C, int Kagg, int Ks)
{
  __shared__ __attribute__((aligned(16))) bf16 As[128 * 32];
  __shared__ __attribute__((aligned(16))) bf16 Bs[128 * 32];
  const int z = blockIdx.y;
  const bf16* A = A0 + (size_t)z * sA;
  const bf16* Bt = B0 + (size_t)z * sB;
  const int tid = threadIdx.x;
  const int w = tid >> 6, l = tid & 63;
  const int tm = blockIdx.x * 128;
  const int wm = (w >> 1) * 64, wn = (w & 1) * 64;
  const int lr = l & 15, q = l >> 4;

  f32x4 acc[4][4] = {};
  const int arow = l >> 2;
  const int acol = (l & 3) * 8;

#define RECOMB_KSTEP(AgP, BgP, LDK)                                            \
  {                                                                            \
    _Pragma("unroll")                                                          \
    for (int i = 0; i < 2; i++) {                                              \
      int rb = __builtin_amdgcn_readfirstlane(16 * (2 * w + i));               \
      GLOAD_LDS16((AgP) + (size_t)(rb + arow) * (LDK) + k0, As + rb * 32);     \
      GLOAD_LDS16((BgP) + (size_t)(rb + arow) * (LDK) + k0, Bs + rb * 32);     \
    }                                                                          \
    __syncthreads();                                                           \
    bf16x8 af[4], bfr[4];                                                      \
    _Pragma("unroll")                                                          \
    for (int i = 0; i < 4; i++)                                                \
      af[i] = *(const bf16x8*)&As[(wm + i * 16 + lr) * 32 + q * 8];            \
    _Pragma("unroll")                                                          \
    for (int jj = 0; jj < 4; jj++)                                             \
      bfr[jj] = *(const bf16x8*)&Bs[(wn + jj * 16 + lr) * 32 + q * 8];         \
    _Pragma("unroll")                                                          \
    for (int i = 0; i < 4; i++)                                                \
      _Pragma("unroll")                                                        \
      for (int jj = 0; jj < 4; jj++)                                           \
        acc[i][jj] = __builtin_amdgcn_mfma_f32_16x16x32_bf16(af[i], bfr[jj],   \
                                                             acc[i][jj], 0, 0, 0); \
    __syncthreads();                                                           \
  }

  {
    const bf16* Ag = A + (size_t)tm * Kagg + acol;
    const bf16* Bg = Bt + acol;
    for (int k0 = 0; k0 < Kagg; k0 += 32) RECOMB_KSTEP(Ag, Bg, Kagg)
  }
  {
    const bf16* Ag = Xs + (size_t)tm * Ks + acol;
    const bf16* Bg = Wskt + (size_t)(z * 128) * Ks + acol;
    for (int k0 = 0; k0 < Ks; k0 += 32) RECOMB_KSTEP(Ag, Bg, Ks)
  }
#undef RECOMB_KSTEP

#pragma unroll
  for (int i = 0; i < 4; i++)
#pragma unroll
    for (int jj = 0; jj < 4; jj++)
#pragma unroll
      for (int r = 0; r < 4; r++) {
        int row = tm + wm + i * 16 + q * 4 + r;
        int col = z * 128 + wn + jj * 16 + lr;
        C[(size_t)row * 512 + col] = acc[i][jj][r];
      }
}

// ---------------------------------------------------------------------------
__global__ void cast_pad_k(const float* __restrict__ src, bf16* __restrict__ dst,
                           long nvalid, long ntot)
{
  long i = ((long)blockIdx.x * 256 + threadIdx.x) * 8;
  if (i >= ntot) return;
  bf16x8 o;
  if (i + 8 <= nvalid) {
    float4 v0 = *(const float4*)(src + i);
    float4 v1 = *(const float4*)(src + i + 4);
    o[0] = (bf16)v0.x; o[1] = (bf16)v0.y; o[2] = (bf16)v0.z; o[3] = (bf16)v0.w;
    o[4] = (bf16)v1.x; o[5] = (bf16)v1.y; o[6] = (bf16)v1.z; o[7] = (bf16)v1.w;
  } else {
#pragma unroll
    for (int t = 0; t < 8; t++)
      o[t] = (i + t < nvalid) ? (bf16)src[i + t] : (bf16)0.f;
  }
  *(bf16x8*)(dst + i) = o;
}

__global__ void transpose_cast_k(const float* __restrict__ W, bf16* __restrict__ Wt,
                                 int K, int Nsrc, int Nvalid)
{
  int n = blockIdx.y;
  int k = blockIdx.x * 256 + threadIdx.x;
  Wt[(size_t)n * K + k] = (n < Nvalid) ? (bf16)W[(size_t)k * Nsrc + n] : (bf16)0.f;
}

// Brec[h][c][j*K+k] = Wt[j*512 + h*128 + c][k]; flat i = ((h*128+c)*NREL + j)*K + k
// NOTE: aggx's K-dim layout is IDENTITY (the agg kernel's chunk-major
// addressing only changes per-instruction lane->address mapping, not the
// stored layout), so Brec needs no permutation.
__global__ void reorder_brec_k(const bf16* __restrict__ Wt, bf16* __restrict__ Brec, int K)
{
  int i = blockIdx.x * 256 + threadIdx.x;
  int k = i % K;
  int rest = i / K;
  int j = rest % NREL;
  int rest2 = rest / NREL;
  int c = rest2 & 127;
  int h = rest2 >> 7;
  Brec[i] = Wt[((size_t)(j * 512 + h * 128 + c)) * K + k];
}

// wvec[col][k] = sum_c W[j][k][h*128+c] * a[j][h][c]; col = j*8 + side*4 + h (<40)
__global__ void wvec_k(const float* __restrict__ W, const float* __restrict__ a_s,
                       const float* __restrict__ a_d, bf16* __restrict__ wv, int K)
{
  int k = blockIdx.x * 64 + threadIdx.x;
  int col = blockIdx.y;
  float v = 0.f;
  if (col < 40) {
    int j = col >> 3, side = (col >> 2) & 1, h = col & 3;
    const float* Wrow = W + ((size_t)j * K + k) * 512 + h * 128;
    const float* av = (side ? a_d : a_s) + (j * 4 + h) * 128;
    for (int c = 0; c < 128; c++) v += Wrow[c] * av[c];
  }
  wv[(size_t)col * K + k] = (bf16)v;
}

// ---------------------------------------------------------------------------
// CSR build
// ---------------------------------------------------------------------------
__global__ void fill_i32_k(int* __restrict__ p, int v, int n)
{
  int i = blockIdx.x * 256 + threadIdx.x;
  if (i < n) p[i] = v;
}

// zero the pad rows [nstart, nstart+rows) of all 4 head planes in one launch
__global__ void pad_zero_k(bf16* __restrict__ aggx, int nstart, int rows, long KT, long NP)
{
  long i = (long)blockIdx.x * 256 + threadIdx.x;
  long tot = (long)rows * KT / 2;
  if (i >= tot) return;
  int* p = (int*)(aggx + ((size_t)blockIdx.y * NP + nstart) * KT);
  p[i] = 0;
}

__global__ void hist_k(const int* __restrict__ et, const int* __restrict__ ed,
                       int* __restrict__ cnt, int E, int ndst)
{
  int e = blockIdx.x * 256 + threadIdx.x;
  if (e >= E) return;
  atomicAdd(&cnt[et[e] * ndst + ed[e]], 1);
}

__global__ void scan1_k(const int* __restrict__ in, int* __restrict__ out,
                        int* __restrict__ bsums, int n)
{
  __shared__ int sh[256];
  int t = threadIdx.x;
  int i = blockIdx.x * 256 + t;
  int v = (i < n) ? in[i] : 0;
  sh[t] = v;
  __syncthreads();
#pragma unroll
  for (int o = 1; o < 256; o <<= 1) {
    int x = 0;
    if (t >= o) x = sh[t - o];
    __syncthreads();
    if (t >= o) sh[t] += x;
    __syncthreads();
  }
  if (i < n) out[i] = sh[t] - v;
  if (t == 255) bsums[blockIdx.x] = sh[255];
}

__global__ void scan2_k(int* __restrict__ b, int n)
{
  __shared__ int sh[1024];
  int t = threadIdx.x;
  int v = (t < n) ? b[t] : 0;
  sh[t] = v;
  __syncthreads();
#pragma unroll
  for (int o = 1; o < 1024; o <<= 1) {
    int x = 0;
    if (t >= o) x = sh[t - o];
    __syncthreads();
    if (t >= o) sh[t] += x;
    __syncthreads();
  }
  if (t < n) b[t] = sh[t] - v;
}

__global__ void add_off_k(int* __restrict__ out, const int* __restrict__ bscan, int n)
{
  int i = blockIdx.x * 256 + threadIdx.x;
  if (i < n) out[i] += bscan[blockIdx.x];
}

__global__ void copy_cursor_k(int* __restrict__ off, int* __restrict__ cur, int n, int E)
{
  int i = blockIdx.x * 256 + threadIdx.x;
  if (i < n) cur[i] = off[i];
  if (i == 0) off[n] = E;
}

__global__ void scatter_k(const int* __restrict__ es, const int* __restrict__ ed,
                          const int* __restrict__ et, int* __restrict__ cur,
                          int* __restrict__ sorted_src, int E, int ndst)
{
  int e = blockIdx.x * 256 + threadIdx.x;
  if (e >= E) return;
  int pos = atomicAdd(&cur[et[e] * ndst + ed[e]], 1);
  sorted_src[pos] = es[e];
}

// ---------------------------------------------------------------------------
// x-space softmax-aggregate — r2 structure (proven 405us) + COALESCED
// chunk-major addressing. grid = (ndst/4, NREL) x 256 threads, one (dst,rel)
// key per wave, depth-1 prefetch, no explicit waits, no LDS.
// Addressing: lane l, chunk c accesses element c*256 + l*4 (64x8B = 512B
// fully contiguous per instruction) instead of the old l*(CH*4)+c*4 strided
// 8B-in-24B pattern (~3x the cacheline/TA work per instruction). The STORED
// layout of aggx is the identity in k either way (only the lane->address
// mapping changes), so downstream consumers are unchanged.
// aggx[h][d][j*K + k] = sum_e alpha[e,h] * X[src_e][k]
// scoresbuf [.][128]: col j*8+h = a_s, col j*8+4+h = a_d
// ---------------------------------------------------------------------------
template <int K, int CH>   // CH = K/256  (bf16x4 chunks per lane)
__global__ __launch_bounds__(256) void agg_x_k(
    const int* __restrict__ sorted_src, const int* __restrict__ off,
    const float* __restrict__ scoresbuf, const bf16* __restrict__ X,
    bf16* __restrict__ aggx, int ndst, int nrows)
{
  const int wv = threadIdx.x >> 6;
  const int l  = threadIdx.x & 63;
  const int d  = blockIdx.x * 4 + wv;
  const int j  = blockIdx.y;
  if (d >= ndst) return;
  const int key = j * ndst + d;
  const int beg = off[key], end = off[key + 1];
  const float4 svd = *(const float4*)(scoresbuf + (size_t)d * 128 + j * 8 + 4);

  const int lbase = l * 4;   // + c*256 per chunk (coalesced)

  float den[4] = {0.f, 0.f, 0.f, 0.f};
  float acc[4][CH * 4] = {};

  int p = beg;
  float4 sv0;
  bf16x4 xv0[CH];
  if (p < end) {
    int s0 = sorted_src[p];
    sv0 = *(const float4*)(scoresbuf + (size_t)s0 * 128 + j * 8);
    const bf16* xr = X + (size_t)s0 * K + lbase;
#pragma unroll
    for (int c = 0; c < CH; c++) xv0[c] = *(const bf16x4*)(xr + c * 256);
  }
  while (p < end) {
    const bool more = (p + 1 < end);
    float4 sv1;
    bf16x4 xv1[CH];
    if (more) {
      int s1 = sorted_src[p + 1];
      sv1 = *(const float4*)(scoresbuf + (size_t)s1 * 128 + j * 8);
      const bf16* xr = X + (size_t)s1 * K + lbase;
#pragma unroll
      for (int c = 0; c < CH; c++) xv1[c] = *(const bf16x4*)(xr + c * 256);
    }
    float v[4] = {sv0.x + svd.x, sv0.y + svd.y, sv0.z + svd.z, sv0.w + svd.w};
    float e[4];
#pragma unroll
    for (int h = 0; h < 4; h++) {
      float sc = v[h] > 0.f ? v[h] : 0.2f * v[h];
      e[h] = __expf(sc);
      den[h] += e[h];
    }
#pragma unroll
    for (int c = 0; c < CH; c++) {
#pragma unroll
      for (int t = 0; t < 4; t++) {
        float f = (float)xv0[c][t];
#pragma unroll
        for (int h = 0; h < 4; h++)
          acc[h][c * 4 + t] += e[h] * f;
      }
    }
    p++;
    if (more) {
      sv0 = sv1;
#pragma unroll
      for (int c = 0; c < CH; c++) xv0[c] = xv1[c];
    }
  }

#pragma unroll
  for (int h = 0; h < 4; h++) {
    float sc = 1.f / fmaxf(den[h], 1e-16f);
    bf16* orow = aggx + ((size_t)h * nrows + d) * ((size_t)NREL * K) + (size_t)j * K + lbase;
#pragma unroll
    for (int c = 0; c < CH; c++) {
      bf16x4 o;
#pragma unroll
      for (int t = 0; t < 4; t++) o[t] = (bf16)(acc[h][c * 4 + t] * sc);
      *(bf16x4*)(orow + c * 256) = o;
    }
  }
}

// ---------------------------------------------------------------------------
__global__ void bias_combine_k(const float* __restrict__ bsk, const float* __restrict__ brel,
                               float* __restrict__ out, int R)
{
  int c = blockIdx.x * 256 + threadIdx.x;
  if (c >= HID) return;
  float v = bsk[c];
  for (int j = 0; j < R; j++) v += brel[j * HID + c];
  out[c] = v;
}

__global__ void fill_f32_k(float* __restrict__ p, float v, int n)
{
  int i = blockIdx.x * 256 + threadIdx.x;
  if (i < n) p[i] = v;
}

__global__ void bn_stats_k(const float* __restrict__ X, const float* __restrict__ bias,
                           float* __restrict__ sums, float* __restrict__ sumsq, int rows)
{
  int t = threadIdx.x;
  int c0 = t * 2;
  float b0 = bias[c0], b1 = bias[c0 + 1];
  float s0 = 0, s1 = 0, q0 = 0, q1 = 0;
  for (int r = blockIdx.x; r < rows; r += gridDim.x) {
    float2 v = *(const float2*)(X + (size_t)r * HID + c0);
    float v0 = v.x + b0, v1 = v.y + b1;
    s0 += v0; q0 += v0 * v0;
    s1 += v1; q1 += v1 * v1;
  }
  atomicAdd(sums + c0, s0); atomicAdd(sums + c0 + 1, s1);
  atomicAdd(sumsq + c0, q0); atomicAdd(sumsq + c0 + 1, q1);
}

template <int ACT>
__global__ void bn_apply_k(const float* __restrict__ X, const float* __restrict__ bias,
                           const float* __restrict__ sums, const float* __restrict__ sumsq,
                           const float* __restrict__ gamma, const float* __restrict__ beta,
                           bf16* __restrict__ Y, int rows, float invN)
{
  int idx = blockIdx.x * 256 + threadIdx.x;
  int row = idx >> 9, c = idx & 511;
  float y = 0.f;
  if (row < rows) {
    float mu = sums[c] * invN;
    float var = sumsq[c] * invN - mu * mu;
    float v = X[idx] + bias[c];
    float xn = (v - mu) * rsqrtf(var + 1e-5f);
    y = gamma[c] * xn + beta[c];
    y = (ACT == 0) ? (y > 0.f ? y : expm1f(y)) : fmaxf(y, 0.f);
  }
  Y[idx] = (bf16)y;
}

// ---------------------------------------------------------------------------
extern "C" void kernel_launch(void* const* d_in, const int* in_sizes, int n_in,
                              void* d_out, int out_size, void* d_ws, size_t ws_size,
                              hipStream_t stream)
{
  const float* x    = (const float*)d_in[0];
  const int*   es0  = (const int*)d_in[1];
  const int*   ed0  = (const int*)d_in[2];
  const int*   et0  = (const int*)d_in[3];
  const int*   es1  = (const int*)d_in[4];
  const int*   ed1  = (const int*)d_in[5];
  const int*   et1  = (const int*)d_in[6];
  const float* W0   = (const float*)d_in[7];
  const float* as0  = (const float*)d_in[8];
  const float* ad0  = (const float*)d_in[9];
  const float* b0   = (const float*)d_in[10];
  const float* Wsk0 = (const float*)d_in[11];
  const float* bsk0 = (const float*)d_in[12];
  const float* g0   = (const float*)d_in[13];
  const float* be0  = (const float*)d_in[14];
  const float* W1   = (const float*)d_in[15];
  const float* as1  = (const float*)d_in[16];
  const float* ad1  = (const float*)d_in[17];
  const float* b1   = (const float*)d_in[18];
  const float* Wsk1 = (const float*)d_in[19];
  const float* bsk1 = (const float*)d_in[20];
  const float* g1   = (const float*)d_in[21];
  const float* be1  = (const float*)d_in[22];
  const float* Wm1  = (const float*)d_in[23];
  const float* bm1  = (const float*)d_in[24];
  const float* gm   = (const float*)d_in[25];
  const float* bmn  = (const float*)d_in[26];
  const float* Wm2  = (const float*)d_in[27];
  const float* bm2  = (const float*)d_in[28];

  char* wsb = (char*)d_ws;
  size_t off = 0;
  auto alloc = [&](size_t bytes) -> char* {
    char* p = wsb + off;
    off = (off + bytes + 255) & ~(size_t)255;
    return p;
  };
  // persistent / small
  bf16*  Wsk0t  = (bf16*)alloc((size_t)HID * K0 * 2);
  bf16*  Wsk1t  = (bf16*)alloc((size_t)HID * HID * 2);
  bf16*  Wm1t   = (bf16*)alloc((size_t)HID * HID * 2);
  bf16*  Wm2t   = (bf16*)alloc((size_t)OUTP * HID * 2);
  bf16*  W0t    = (bf16*)alloc((size_t)NREL * HID * K0 * 2);
  bf16*  W1t    = (bf16*)alloc((size_t)NREL * HID * HID * 2);
  bf16*  Brec0  = (bf16*)alloc((size_t)4 * 128 * NREL * K0 * 2);
  bf16*  Brec1  = (bf16*)alloc((size_t)4 * 128 * NREL * HID * 2);
  bf16*  wvec0  = (bf16*)alloc((size_t)128 * K0 * 2);
  bf16*  wvec1  = (bf16*)alloc((size_t)128 * HID * 2);
  float* biasb  = (float*)alloc(HID * 4);
  float* statsb = (float*)alloc(1024 * 4);
  int*   offb   = (int*)alloc((size_t)(NREL * N1 + 1) * 4);
  int*   curb   = (int*)alloc((size_t)NREL * N1 * 4);
  int*   bsumsb = (int*)alloc(1024 * 4);
  int*   srtb   = (int*)alloc((size_t)E0 * 4);
  float* out0   = (float*)alloc((size_t)N1P * HID * 4);
  bf16*  h1b    = (bf16*)alloc((size_t)N1P * HID * 2);
  bf16*  h2b    = (bf16*)alloc((size_t)N2P * HID * 2);
  bf16*  zbb    = (bf16*)alloc((size_t)N2P * HID * 2);
  float* out1   = (float*)alloc((size_t)N2P * HID * 4);
  float* zf     = (float*)alloc((size_t)N2P * HID * 4);
  // big regions
  bf16*  xb        = (bf16*)alloc((size_t)M0P * K0 * 2);
  float* scoresbuf = (float*)alloc((size_t)M0P * 128 * 4);
  bf16*  aggx      = (bf16*)alloc((size_t)4 * N1P * NREL * K0 * 2);  // reused for layer 1

  auto build_csr = [&](const int* es, const int* ed, const int* et, int E, int ndst) {
    int nkeys = NREL * ndst;
    int nbE = (E + 255) / 256;
    int nbK = (nkeys + 255) / 256;
    fill_i32_k<<<nbK, 256, 0, stream>>>(curb, 0, nkeys);
    hist_k<<<nbE, 256, 0, stream>>>(et, ed, curb, E, ndst);
    scan1_k<<<nbK, 256, 0, stream>>>(curb, offb, bsumsb, nkeys);
    scan2_k<<<1, 1024, 0, stream>>>(bsumsb, nbK);
    add_off_k<<<nbK, 256, 0, stream>>>(offb, bsumsb, nkeys);
    copy_cursor_k<<<nbK, 256, 0, stream>>>(offb, curb, nkeys, E);
    scatter_k<<<nbE, 256, 0, stream>>>(es, ed, et, curb, srtb, E, ndst);
  };

  // ---- weight prep ----
  cast_pad_k<<<((size_t)M0P * K0 / 8 + 255) / 256, 256, 0, stream>>>(
      x, xb, (long)M0 * K0, (long)M0P * K0);
  for (int j = 0; j < NREL; j++)
    transpose_cast_k<<<dim3(3, 512), 256, 0, stream>>>(
        W0 + (size_t)j * K0 * HID, W0t + (size_t)j * HID * K0, K0, HID, HID);
  transpose_cast_k<<<dim3(3, 512), 256, 0, stream>>>(Wsk0, Wsk0t, K0, HID, HID);
  for (int j = 0; j < NREL; j++)
    transpose_cast_k<<<dim3(2, 512), 256, 0, stream>>>(
        W1 + (size_t)j * HID * HID, W1t + (size_t)j * HID * HID, HID, HID, HID);
  transpose_cast_k<<<dim3(2, 512), 256, 0, stream>>>(Wsk1, Wsk1t, HID, HID, HID);
  transpose_cast_k<<<dim3(2, 512), 256, 0, stream>>>(Wm1, Wm1t, HID, HID, HID);
  transpose_cast_k<<<dim3(2, OUTP), 256, 0, stream>>>(Wm2, Wm2t, HID, OUTC, OUTC);
  reorder_brec_k<<<(4 * 128 * NREL * K0) / 256, 256, 0, stream>>>(W0t, Brec0, K0);
  reorder_brec_k<<<(4 * 128 * NREL * HID) / 256, 256, 0, stream>>>(W1t, Brec1, HID);
  wvec_k<<<dim3(K0 / 64, 128), 64, 0, stream>>>(W0, as0, ad0, wvec0, K0);
  wvec_k<<<dim3(HID / 64, 128), 64, 0, stream>>>(W1, as1, ad1, wvec1, HID);

  // ---- layer 0 ----
  {
    const int KT = NREL * K0;  // 3840
    build_csr(es0, ed0, et0, E0, N1);
    gemm_bt<1><<<dim3(M0P / 128, 1), 256, 0, stream>>>(xb, wvec0, scoresbuf, 128, K0, 0, 0, 0, nullptr);
    pad_zero_k<<<dim3(((N1P - N1) * KT / 2 + 255) / 256, 4), 256, 0, stream>>>(
        aggx, N1, N1P - N1, KT, N1P);
    agg_x_k<K0, K0 / 256><<<dim3(N1 / 4, NREL), 256, 0, stream>>>(
        srtb, offb, scoresbuf, xb, aggx, N1, N1P);
    gemm_recomb_fused<<<dim3(N1P / 128, 4), 256, 0, stream>>>(
        aggx, (size_t)N1P * KT, Brec0, (size_t)128 * KT, xb, Wsk0t, out0, KT, K0);
    bias_combine_k<<<2, 256, 0, stream>>>(bsk0, b0, biasb, NREL);
    fill_f32_k<<<4, 256, 0, stream>>>(statsb, 0.f, 1024);
    bn_stats_k<<<256, 256, 0, stream>>>(out0, biasb, statsb, statsb + 512, N1);
    bn_apply_k<0><<<(N1P * HID) / 256, 256, 0, stream>>>(out0, biasb, statsb, statsb + 512,
                                                         g0, be0, h1b, N1, 1.f / N1);
  }

  // ---- layer 1 ----
  {
    const int KT = NREL * HID;  // 2560
    build_csr(es1, ed1, et1, E1, N2);
    gemm_bt<1><<<dim3(N1P / 128, 1), 256, 0, stream>>>(h1b, wvec1, scoresbuf, 128, HID, 0, 0, 0, nullptr);
    pad_zero_k<<<dim3(((N2P - N2) * KT / 2 + 255) / 256, 4), 256, 0, stream>>>(
        aggx, N2, N2P - N2, KT, N2P);
    agg_x_k<HID, HID / 256><<<dim3(N2 / 4, NREL), 256, 0, stream>>>(
        srtb, offb, scoresbuf, h1b, aggx, N2, N2P);
    gemm_recomb_fused<<<dim3(N2P / 128, 4), 256, 0, stream>>>(
        aggx, (size_t)N2P * KT, Brec1, (size_t)128 * KT, h1b, Wsk1t, out1, KT, HID);
    bias_combine_k<<<2, 256, 0, stream>>>(bsk1, b1, biasb, NREL);
    fill_f32_k<<<4, 256, 0, stream>>>(statsb, 0.f, 1024);
    bn_stats_k<<<256, 256, 0, stream>>>(out1, biasb, statsb, statsb + 512, N2);
    bn_apply_k<0><<<(N2P * HID) / 256, 256, 0, stream>>>(out1, biasb, statsb, statsb + 512,
                                                         g1, be1, h2b, N2, 1.f / N2);
  }

  // ---- MLP head ----
  gemm_bt<1><<<dim3(N2P / 128, 4), 256, 0, stream>>>(h2b, Wm1t, zf, HID, HID, 0, 0, 0, nullptr);
  fill_f32_k<<<4, 256, 0, stream>>>(statsb, 0.f, 1024);
  bn_stats_k<<<256, 256, 0, stream>>>(zf, bm1, statsb, statsb + 512, N2);
  bn_apply_k<1><<<(N2P * HID) / 256, 256, 0, stream>>>(zf, bm1, statsb, statsb + 512,
                                                       gm, bmn, zbb, N2, 1.f / N2);
  gemm_bt<2><<<dim3(N2P / 128, OUTP / 128), 256, 0, stream>>>(
      zbb, Wm2t, d_out, OUTP, HID, N2, OUTC, OUTC, bm2);

  (void)in_sizes; (void)n_in; (void)out_size; (void)ws_size;
}